// Round 4
// baseline (8904.623 us; speedup 1.0000x reference)
//
#include <hip/hip_runtime.h>
#include <hip/hip_fp16.h>

typedef __half f16;

#define NN   100000   // nodes
#define NE   1600000  // edges
#define CIN  256
#define CH   128
#define COUT 64
#define NB   64

// ---------------- small utility kernels ----------------
__global__ void k_init(float* __restrict__ dinv, float* __restrict__ pool,
                       float* __restrict__ cnt) {
    int i = blockIdx.x * 256 + threadIdx.x;
    if (i < NN) dinv[i] = 1.0f;          // degree starts at 1 (self loop)
    if (i < NB * CH) pool[i] = 0.0f;
    if (i < NB) cnt[i] = 0.0f;
}

__global__ void k_deg(const int* __restrict__ dst, float* __restrict__ deg) {
    int e = blockIdx.x * 256 + threadIdx.x;
    if (e < NE) atomicAdd(&deg[dst[e]], 1.0f);
}

__global__ void k_rsqrt(float* __restrict__ dinv) {
    int i = blockIdx.x * 256 + threadIdx.x;
    if (i < NN) dinv[i] = rsqrtf(dinv[i]);
}

// ---------------- GEMM: C[N,M] = A[N,K] @ W[K,M] ----------------
// 256 threads, 64 rows x M cols per block, K staged in 64-chunks in LDS.
// DUAL: C[row,col] = v * dinv[row]^2 (f32 self-loop term), C2[row,col] = (f16)v.
//       In-place safe when A==C: rows are read only by the block that writes them,
//       and all reads precede the epilogue writes.
template <int M, bool BIAS, bool RELU, bool ACCUM, bool DUAL, typename TA, typename TO>
__global__ __launch_bounds__(256) void k_gemm(const TA* __restrict__ A,
                                              const float* __restrict__ W,
                                              const float* __restrict__ bias,
                                              TO* __restrict__ C,
                                              f16* __restrict__ C2,
                                              const float* __restrict__ dinv,
                                              int K) {
    constexpr int KC = 64, BR = 64;
    constexpr int CG = M / 4;        // column groups (4 cols each)
    constexpr int TYN = 256 / CG;    // row groups
    constexpr int RPT = BR / TYN;    // rows per thread
    __shared__ float Wl[KC * M];
    __shared__ float Al[BR * (KC + 1)];
    const int tid = threadIdx.x;
    const int tx = tid % CG, ty = tid / CG;
    const int rb = blockIdx.x * BR;

    float acc[RPT][4];
#pragma unroll
    for (int r = 0; r < RPT; ++r)
        acc[r][0] = acc[r][1] = acc[r][2] = acc[r][3] = 0.0f;

    for (int k0 = 0; k0 < K; k0 += KC) {
        __syncthreads();
        for (int idx = tid; idx < KC * M; idx += 256)
            Wl[idx] = W[(size_t)(k0 + idx / M) * M + (idx % M)];
        for (int idx = tid; idx < BR * KC; idx += 256) {
            int kk = idx % KC, r = idx / KC;
            int row = rb + r;
            Al[r * (KC + 1) + kk] =
                (row < NN) ? (float)A[(size_t)row * K + k0 + kk] : 0.0f;
        }
        __syncthreads();
#pragma unroll 4
        for (int kk = 0; kk < KC; ++kk) {
            const float4 w = *(const float4*)&Wl[kk * M + tx * 4];
#pragma unroll
            for (int r = 0; r < RPT; ++r) {
                float a = Al[(ty * RPT + r) * (KC + 1) + kk];
                acc[r][0] += a * w.x;
                acc[r][1] += a * w.y;
                acc[r][2] += a * w.z;
                acc[r][3] += a * w.w;
            }
        }
    }
#pragma unroll
    for (int r = 0; r < RPT; ++r) {
        int row = rb + ty * RPT + r;
        if (row >= NN) continue;
        size_t base = (size_t)row * M + tx * 4;
        float sl = 0.0f;
        if (DUAL) { sl = dinv[row]; sl *= sl; }
#pragma unroll
        for (int c = 0; c < 4; ++c) {
            float v = acc[r][c];
            if (BIAS) v += bias[tx * 4 + c];
            if (RELU) v = fmaxf(v, 0.0f);
            if (DUAL) {
                ((float*)C)[base + c] = v * sl;   // self-loop term, f32
                C2[base + c] = (f16)v;            // lin for edge messages
            } else {
                if (ACCUM) v += (float)C[base + c];
                C[base + c] = (TO)v;
            }
        }
    }
}

// ---------------- aggregation ----------------
// agg[dst] += lin[src] * dinv[src]*dinv[dst], 4 features per work item
__global__ void k_scatter(const int* __restrict__ src, const int* __restrict__ dst,
                          const float* __restrict__ dinv,
                          const f16* __restrict__ lin, float* __restrict__ agg) {
    int gid = blockIdx.x * 256 + threadIdx.x;  // NE*32 work items
    int e = gid >> 5;
    if (e >= NE) return;
    int f = gid & 31;
    int s = src[e], d = dst[e];
    float w = dinv[s] * dinv[d];
    const f16* lp = lin + (size_t)s * CH + f * 4;
    float2 raw = *(const float2*)lp;             // 4 halves, 8B aligned
    __half2 h01 = *(__half2*)&raw.x;
    __half2 h23 = *(__half2*)&raw.y;
    float2 f01 = __half22float2(h01);
    float2 f23 = __half22float2(h23);
    float* ap = &agg[(size_t)d * CH + f * 4];
    atomicAdd(ap + 0, f01.x * w);
    atomicAdd(ap + 1, f01.y * w);
    atomicAdd(ap + 2, f23.x * w);
    atomicAdd(ap + 3, f23.y * w);
}

// h = relu((h + b) * (g/sqrt(1+eps)) + be)
__global__ void k_post(float4* __restrict__ h, const float* __restrict__ bias,
                       const float* __restrict__ g, const float* __restrict__ be) {
    const float inv_sqrt = 0.99999500003749968f;  // 1/sqrt(1+1e-5)
    int i = blockIdx.x * 256 + threadIdx.x;       // over NN*32
    if (i >= NN * 32) return;
    int j = (i & 31) * 4;
    float4 v = h[i];
    float vv[4] = {v.x, v.y, v.z, v.w};
#pragma unroll
    for (int c = 0; c < 4; ++c) {
        float t = (vv[c] + bias[j + c]) * (g[j + c] * inv_sqrt) + be[j + c];
        vv[c] = fmaxf(t, 0.0f);
    }
    h[i] = make_float4(vv[0], vv[1], vv[2], vv[3]);
}

// ---------------- pooling ----------------
__global__ void k_count(const int* __restrict__ batch, float* __restrict__ cnt) {
    __shared__ float hist[NB];
    int tid = threadIdx.x;
    if (tid < NB) hist[tid] = 0.0f;
    __syncthreads();
    int n = blockIdx.x * 256 + tid;
    if (n < NN) atomicAdd(&hist[batch[n]], 1.0f);
    __syncthreads();
    if (tid < NB && hist[tid] != 0.0f) atomicAdd(&cnt[tid], hist[tid]);
}

// 128 threads (one per feature), 64 consecutive nodes; correct for any batch order
__global__ void k_pool(const float* __restrict__ h, const int* __restrict__ batch,
                       float* __restrict__ pool) {
    int n0 = blockIdx.x * 64;
    int j = threadIdx.x;
    int cur = batch[n0];
    float acc = 0.0f;
    int nend = (n0 + 64 < NN) ? n0 + 64 : NN;
    for (int n = n0; n < nend; ++n) {
        int b = batch[n];
        if (b != cur) {
            atomicAdd(&pool[cur * CH + j], acc);
            acc = 0.0f;
            cur = b;
        }
        acc += h[(size_t)n * CH + j];
    }
    atomicAdd(&pool[cur * CH + j], acc);
}

__global__ void k_pool_fin(const float* __restrict__ pool,
                           const float* __restrict__ cnt,
                           float* __restrict__ out) {
    int i = blockIdx.x * 256 + threadIdx.x;
    if (i < NB * CH) {
        float c = fmaxf(cnt[i / CH], 1.0f);
        out[i] = pool[i] / c;
    }
}

// ---------------- launch ----------------
extern "C" void kernel_launch(void* const* d_in, const int* in_sizes, int n_in,
                              void* d_out, int out_size, void* d_ws, size_t ws_size,
                              hipStream_t stream) {
    // ---- workspace layout (77.3 MB) ----
    const size_t HB_BYTES = (size_t)NN * CH * 4;   // 51.2 MB f32 h/agg
    const size_t LB_BYTES = (size_t)NN * CH * 2;   // 25.6 MB f16 lin
    const size_t DV_BYTES = (size_t)NN * 4;
    const size_t PL_BYTES = (size_t)NB * CH * 4;
    char* wsb = (char*)d_ws;
    float* hbuf = (float*)wsb;                       // [NN, CH] f32
    f16*   lbuf = (f16*)(wsb + HB_BYTES);            // [NN, CH] f16
    float* dinv = (float*)(wsb + HB_BYTES + LB_BYTES);
    float* pool = (float*)(wsb + HB_BYTES + LB_BYTES + DV_BYTES);
    float* cnt  = (float*)(wsb + HB_BYTES + LB_BYTES + DV_BYTES + PL_BYTES);

    const float* x   = (const float*)d_in[0];
    const int*   ei  = (const int*)d_in[1];
    const int*   bat = (const int*)d_in[2];
    const float* W0 = (const float*)d_in[3],  *b0 = (const float*)d_in[4];
    const float* W1 = (const float*)d_in[5],  *b1 = (const float*)d_in[6];
    const float* W2 = (const float*)d_in[7],  *b2 = (const float*)d_in[8];
    const float* g0 = (const float*)d_in[9],  *be0 = (const float*)d_in[10];
    const float* g1 = (const float*)d_in[11], *be1 = (const float*)d_in[12];
    const float* g2 = (const float*)d_in[13], *be2 = (const float*)d_in[14];
    const float* Wres = (const float*)d_in[15], *bres = (const float*)d_in[16];
    const float* Wl0 = (const float*)d_in[17], *bl0 = (const float*)d_in[18];
    const float* Wl1 = (const float*)d_in[19], *bl1 = (const float*)d_in[20];

    const int* src = ei;
    const int* dst = ei + NE;

    float* outp  = (float*)d_out;                  // [NN, COUT] f32
    float* poolp = outp + (size_t)NN * COUT;       // [NB, CH] f32

    const int gN   = (NN + 255) / 256;            // 391
    const int gE   = (NE + 255) / 256;            // 6250
    const int gNH4 = (NN * 32) / 256;             // 12500
    const int gSc  = (NE * 32) / 256;             // 200000
    const int gRow = (NN + 63) / 64;              // 1563

    // degrees
    k_init<<<gN, 256, 0, stream>>>(dinv, pool, cnt);
    k_deg<<<gE, 256, 0, stream>>>(dst, dinv);
    k_rsqrt<<<gN, 256, 0, stream>>>(dinv);

    // ---- layer 0: hbuf = (x@W0)*dinv^2, lbuf = f16(x@W0) ----
    k_gemm<CH, false, false, false, true, float, float>
        <<<gRow, 256, 0, stream>>>(x, W0, nullptr, hbuf, lbuf, dinv, CIN);
    k_scatter<<<gSc, 256, 0, stream>>>(src, dst, dinv, lbuf, hbuf);
    k_post<<<gNH4, 256, 0, stream>>>((float4*)hbuf, b0, g0, be0);
    // residual: h += x @ Wres + bres
    k_gemm<CH, true, false, true, false, float, float>
        <<<gRow, 256, 0, stream>>>(x, Wres, bres, hbuf, nullptr, nullptr, CIN);

    // ---- layer 1 (GEMM in-place on hbuf) ----
    k_gemm<CH, false, false, false, true, float, float>
        <<<gRow, 256, 0, stream>>>(hbuf, W1, nullptr, hbuf, lbuf, dinv, CH);
    k_scatter<<<gSc, 256, 0, stream>>>(src, dst, dinv, lbuf, hbuf);
    k_post<<<gNH4, 256, 0, stream>>>((float4*)hbuf, b1, g1, be1);

    // ---- layer 2 ----
    k_gemm<CH, false, false, false, true, float, float>
        <<<gRow, 256, 0, stream>>>(hbuf, W2, nullptr, hbuf, lbuf, dinv, CH);
    k_scatter<<<gSc, 256, 0, stream>>>(src, dst, dinv, lbuf, hbuf);
    k_post<<<gNH4, 256, 0, stream>>>((float4*)hbuf, b2, g2, be2);

    // ---- mean pool over graphs (uses final h) ----
    k_count<<<gN, 256, 0, stream>>>(bat, cnt);
    k_pool<<<gRow, 128, 0, stream>>>(hbuf, bat, pool);
    k_pool_fin<<<(NB * CH + 255) / 256, 256, 0, stream>>>(pool, cnt, poolp);

    // ---- head MLP: out = relu(h@Wl0+bl0) @ Wl1 + bl1 ----
    k_gemm<CH, true, true, false, false, float, f16>
        <<<gRow, 256, 0, stream>>>(hbuf, Wl0, bl0, lbuf, nullptr, nullptr, CH);
    k_gemm<COUT, true, false, false, false, f16, float>
        <<<gRow, 256, 0, stream>>>(lbuf, Wl1, bl1, outp, nullptr, nullptr, CH);
}

// Round 5
// 1450.742 us; speedup vs baseline: 6.1380x; 6.1380x over previous
//
#include <hip/hip_runtime.h>
#include <hip/hip_fp16.h>

typedef __half f16;

#define NN   100000   // nodes
#define NE   1600000  // edges
#define CIN  256
#define CH   128
#define COUT 64
#define NB   64

// ---------------- diagnostics ----------------
__global__ void k_sentinel(float* __restrict__ out, int n, float val) {
    int i = blockIdx.x * 256 + threadIdx.x;
    if (i < n) out[i] = val;
}

// ---------------- setup kernels ----------------
__global__ void k_init(int* __restrict__ deg, float* __restrict__ pool,
                       float* __restrict__ cnt) {
    int i = blockIdx.x * 256 + threadIdx.x;
    if (i < NN) deg[i] = 0;
    if (i < NB * CH) pool[i] = 0.0f;
    if (i < NB) cnt[i] = 0.0f;
}

__global__ void k_deg(const int* __restrict__ dst, int* __restrict__ deg) {
    int e = blockIdx.x * 256 + threadIdx.x;
    if (e < NE) atomicAdd(&deg[dst[e]], 1);
}

// single-block inclusive scan: rowptr[i+1] = sum deg[0..i], rowptr[0]=0
__global__ void k_scan(const int* __restrict__ deg, int* __restrict__ rowptr) {
    __shared__ int wsum[4];
    __shared__ int carry, carry_next;
    const int tid = threadIdx.x, lane = tid & 63, wv = tid >> 6;
    if (tid == 0) carry = 0;
    __syncthreads();
    for (int base = 0; base < NN; base += 256) {
        int i = base + tid;
        int v = (i < NN) ? deg[i] : 0;
#pragma unroll
        for (int off = 1; off < 64; off <<= 1) {
            int t = __shfl_up(v, off);
            if (lane >= off) v += t;
        }
        if (lane == 63) wsum[wv] = v;
        __syncthreads();
        int add = carry;
        for (int w = 0; w < wv; ++w) add += wsum[w];
        int incl = v + add;
        if (i < NN) rowptr[i + 1] = incl;
        if (tid == 255) carry_next = incl;
        __syncthreads();
        if (tid == 0) carry = carry_next;
        __syncthreads();
    }
    if (threadIdx.x == 0) rowptr[0] = 0;
}

// dinv = rsqrt(deg+1);  cursor = rowptr (fill cursors)
__global__ void k_dinv_cur(const int* __restrict__ deg, const int* __restrict__ rowptr,
                           float* __restrict__ dinv, int* __restrict__ cursor) {
    int i = blockIdx.x * 256 + threadIdx.x;
    if (i < NN) {
        dinv[i] = rsqrtf((float)deg[i] + 1.0f);
        cursor[i] = rowptr[i];
    }
}

__global__ void k_fill(const int* __restrict__ src, const int* __restrict__ dst,
                       int* __restrict__ cursor, int* __restrict__ csr) {
    int e = blockIdx.x * 256 + threadIdx.x;
    if (e < NE) {
        int pos = atomicAdd(&cursor[dst[e]], 1);
        csr[pos] = src[e];
    }
}

// ---------------- GEMM: C[N,M] = A[N,K] @ W[K,M] ----------------
// 256 threads, 64 rows x M cols per block, K staged in 64-chunks in LDS.
// DUAL: writes ONLY C2[row,col] = (f16)((v)*dinv[row])  (pre-scaled message).
template <int M, bool BIAS, bool RELU, bool ACCUM, bool DUAL, typename TA, typename TO>
__global__ __launch_bounds__(256) void k_gemm(const TA* __restrict__ A,
                                              const float* __restrict__ W,
                                              const float* __restrict__ bias,
                                              TO* __restrict__ C,
                                              f16* __restrict__ C2,
                                              const float* __restrict__ dinv,
                                              int K) {
    constexpr int KC = 64, BR = 64;
    constexpr int CG = M / 4;        // column groups (4 cols each)
    constexpr int TYN = 256 / CG;    // row groups
    constexpr int RPT = BR / TYN;    // rows per thread
    __shared__ float Wl[KC * M];
    __shared__ float Al[BR * (KC + 1)];
    const int tid = threadIdx.x;
    const int tx = tid % CG, ty = tid / CG;
    const int rb = blockIdx.x * BR;

    float acc[RPT][4];
#pragma unroll
    for (int r = 0; r < RPT; ++r)
        acc[r][0] = acc[r][1] = acc[r][2] = acc[r][3] = 0.0f;

    for (int k0 = 0; k0 < K; k0 += KC) {
        __syncthreads();
        for (int idx = tid; idx < KC * M; idx += 256)
            Wl[idx] = W[(size_t)(k0 + idx / M) * M + (idx % M)];
        for (int idx = tid; idx < BR * KC; idx += 256) {
            int kk = idx % KC, r = idx / KC;
            int row = rb + r;
            Al[r * (KC + 1) + kk] =
                (row < NN) ? (float)A[(size_t)row * K + k0 + kk] : 0.0f;
        }
        __syncthreads();
#pragma unroll 4
        for (int kk = 0; kk < KC; ++kk) {
            const float4 w = *(const float4*)&Wl[kk * M + tx * 4];
#pragma unroll
            for (int r = 0; r < RPT; ++r) {
                float a = Al[(ty * RPT + r) * (KC + 1) + kk];
                acc[r][0] += a * w.x;
                acc[r][1] += a * w.y;
                acc[r][2] += a * w.z;
                acc[r][3] += a * w.w;
            }
        }
    }
#pragma unroll
    for (int r = 0; r < RPT; ++r) {
        int row = rb + ty * RPT + r;
        if (row >= NN) continue;
        size_t base = (size_t)row * M + tx * 4;
        float sl = DUAL ? dinv[row] : 0.0f;
#pragma unroll
        for (int c = 0; c < 4; ++c) {
            float v = acc[r][c];
            if (BIAS) v += bias[tx * 4 + c];
            if (RELU) v = fmaxf(v, 0.0f);
            if (DUAL) {
                C2[base + c] = (f16)(v * sl);     // pre-scaled message
            } else {
                if (ACCUM) v += (float)C[base + c];
                C[base + c] = (TO)v;
            }
        }
    }
}

// ---------------- CSR gather + BN + ReLU ----------------
// one wave per dst node; lane holds features [2*lane, 2*lane+1]
// h[d] = relu(( dinv[d]*(linscaled[d] + sum_edges linscaled[src]) + b )*g' + be)
__global__ __launch_bounds__(256) void k_gather(const int* __restrict__ rowptr,
                                                const int* __restrict__ csr,
                                                const float* __restrict__ dinv,
                                                const f16* __restrict__ lin,
                                                float* __restrict__ h,
                                                const float* __restrict__ b,
                                                const float* __restrict__ g,
                                                const float* __restrict__ be) {
    const int gw = (blockIdx.x * 256 + threadIdx.x) >> 6;   // dst node
    const int lane = threadIdx.x & 63;
    if (gw >= NN) return;
    const __half2* lp = (const __half2*)lin;
    const int start = rowptr[gw], end = rowptr[gw + 1];

    float2 acc = __half22float2(lp[(size_t)gw * 64 + lane]);  // self term
    int j = start;
    for (; j + 3 < end; j += 4) {
        int s0 = csr[j], s1 = csr[j + 1], s2 = csr[j + 2], s3 = csr[j + 3];
        float2 v0 = __half22float2(lp[(size_t)s0 * 64 + lane]);
        float2 v1 = __half22float2(lp[(size_t)s1 * 64 + lane]);
        float2 v2 = __half22float2(lp[(size_t)s2 * 64 + lane]);
        float2 v3 = __half22float2(lp[(size_t)s3 * 64 + lane]);
        acc.x += v0.x + v1.x + v2.x + v3.x;
        acc.y += v0.y + v1.y + v2.y + v3.y;
    }
    for (; j < end; ++j) {
        int s = csr[j];
        float2 v = __half22float2(lp[(size_t)s * 64 + lane]);
        acc.x += v.x;
        acc.y += v.y;
    }
    const float inv_sqrt = 0.99999500003749968f;  // 1/sqrt(1+1e-5)
    float dv = dinv[gw];
    int f = lane * 2;
    float2 bb = *(const float2*)&b[f];
    float2 gg = *(const float2*)&g[f];
    float2 ee = *(const float2*)&be[f];
    float t0 = (acc.x * dv + bb.x) * (gg.x * inv_sqrt) + ee.x;
    float t1 = (acc.y * dv + bb.y) * (gg.y * inv_sqrt) + ee.y;
    ((float2*)h)[(size_t)gw * 64 + lane] = make_float2(fmaxf(t0, 0.0f), fmaxf(t1, 0.0f));
}

// ---------------- pooling ----------------
__global__ void k_count(const int* __restrict__ batch, float* __restrict__ cnt) {
    __shared__ float hist[NB];
    int tid = threadIdx.x;
    if (tid < NB) hist[tid] = 0.0f;
    __syncthreads();
    int n = blockIdx.x * 256 + tid;
    if (n < NN) atomicAdd(&hist[batch[n]], 1.0f);
    __syncthreads();
    if (tid < NB && hist[tid] != 0.0f) atomicAdd(&cnt[tid], hist[tid]);
}

// 128 threads (one per feature), 64 consecutive nodes; correct for any sorted batch
__global__ void k_pool(const float* __restrict__ h, const int* __restrict__ batch,
                       float* __restrict__ pool) {
    int n0 = blockIdx.x * 64;
    int j = threadIdx.x;
    int cur = batch[n0];
    float acc = 0.0f;
    int nend = (n0 + 64 < NN) ? n0 + 64 : NN;
    for (int n = n0; n < nend; ++n) {
        int b = batch[n];
        if (b != cur) {
            atomicAdd(&pool[cur * CH + j], acc);
            acc = 0.0f;
            cur = b;
        }
        acc += h[(size_t)n * CH + j];
    }
    atomicAdd(&pool[cur * CH + j], acc);
}

__global__ void k_pool_fin(const float* __restrict__ pool,
                           const float* __restrict__ cnt,
                           float* __restrict__ out) {
    int i = blockIdx.x * 256 + threadIdx.x;
    if (i < NB * CH) {
        float c = fmaxf(cnt[i / CH], 1.0f);
        out[i] = pool[i] / c;
    }
}

// ---------------- launch ----------------
extern "C" void kernel_launch(void* const* d_in, const int* in_sizes, int n_in,
                              void* d_out, int out_size, void* d_ws, size_t ws_size,
                              hipStream_t stream) {
    float* outp  = (float*)d_out;                  // [NN, COUT] f32
    float* poolp = outp + (size_t)NN * COUT;       // [NB, CH] f32

    // ---- workspace layout (~84.9 MB) ----
    const size_t HB = (size_t)NN * CH * 4;         // 51.2 MB f32 h
    const size_t LB = (size_t)NN * CH * 2;         // 25.6 MB f16 linscaled
    const size_t DV = (size_t)NN * 4;              // dinv
    const size_t RP = (size_t)(NN + 1) * 4;        // rowptr
    const size_t CU = (size_t)NN * 4;              // cursor
    const size_t CS = (size_t)NE * 4;              // csr
    const size_t DG = (size_t)NN * 4;              // deg
    const size_t PL = (size_t)NB * CH * 4;
    const size_t CT = (size_t)NB * 4;
    const size_t need = HB + LB + DV + RP + CU + CS + DG + PL + CT;
    if (ws_size < need) {
        k_sentinel<<<(out_size + 255) / 256, 256, 0, stream>>>(outp, out_size, 2000.0f);
        return;
    }
    char* p = (char*)d_ws;
    float* hbuf   = (float*)p;             p += HB;
    f16*   lbuf   = (f16*)p;               p += LB;
    float* dinv   = (float*)p;             p += DV;
    int*   rowptr = (int*)p;               p += RP;
    int*   cursor = (int*)p;               p += CU;
    int*   csr    = (int*)p;               p += CS;
    int*   deg    = (int*)p;               p += DG;
    float* pool   = (float*)p;             p += PL;
    float* cnt    = (float*)p;

    const float* x   = (const float*)d_in[0];
    const int*   ei  = (const int*)d_in[1];
    const int*   bat = (const int*)d_in[2];
    const float* W0 = (const float*)d_in[3],  *b0 = (const float*)d_in[4];
    const float* W1 = (const float*)d_in[5],  *b1 = (const float*)d_in[6];
    const float* W2 = (const float*)d_in[7],  *b2 = (const float*)d_in[8];
    const float* g0 = (const float*)d_in[9],  *be0 = (const float*)d_in[10];
    const float* g1 = (const float*)d_in[11], *be1 = (const float*)d_in[12];
    const float* g2 = (const float*)d_in[13], *be2 = (const float*)d_in[14];
    const float* Wres = (const float*)d_in[15], *bres = (const float*)d_in[16];
    const float* Wl0 = (const float*)d_in[17], *bl0 = (const float*)d_in[18];
    const float* Wl1 = (const float*)d_in[19], *bl1 = (const float*)d_in[20];

    const int* src = ei;
    const int* dst = ei + NE;

    const int gN   = (NN + 255) / 256;            // 391
    const int gE   = (NE + 255) / 256;            // 6250
    const int gRow = (NN + 63) / 64;              // 1563
    const int gGat = (NN * 64) / 256;             // 25000 (exact)

    // ---- degrees + CSR build ----
    k_init<<<gN, 256, 0, stream>>>(deg, pool, cnt);
    k_deg<<<gE, 256, 0, stream>>>(dst, deg);
    k_scan<<<1, 256, 0, stream>>>(deg, rowptr);
    k_dinv_cur<<<gN, 256, 0, stream>>>(deg, rowptr, dinv, cursor);
    k_fill<<<gE, 256, 0, stream>>>(src, dst, cursor, csr);

    // ---- layer 0: lbuf = f16((x@W0)*dinv[row]); gather+BN+ReLU -> hbuf ----
    k_gemm<CH, false, false, false, true, float, float>
        <<<gRow, 256, 0, stream>>>(x, W0, nullptr, nullptr, lbuf, dinv, CIN);
    k_gather<<<gGat, 256, 0, stream>>>(rowptr, csr, dinv, lbuf, hbuf, b0, g0, be0);
    // residual: h += x @ Wres + bres
    k_gemm<CH, true, false, true, false, float, float>
        <<<gRow, 256, 0, stream>>>(x, Wres, bres, hbuf, nullptr, nullptr, CIN);

    // ---- layer 1 ----
    k_gemm<CH, false, false, false, true, float, float>
        <<<gRow, 256, 0, stream>>>(hbuf, W1, nullptr, nullptr, lbuf, dinv, CH);
    k_gather<<<gGat, 256, 0, stream>>>(rowptr, csr, dinv, lbuf, hbuf, b1, g1, be1);

    // ---- layer 2 ----
    k_gemm<CH, false, false, false, true, float, float>
        <<<gRow, 256, 0, stream>>>(hbuf, W2, nullptr, nullptr, lbuf, dinv, CH);
    k_gather<<<gGat, 256, 0, stream>>>(rowptr, csr, dinv, lbuf, hbuf, b2, g2, be2);

    // ---- mean pool over graphs (final h) ----
    k_count<<<gN, 256, 0, stream>>>(bat, cnt);
    k_pool<<<gRow, 128, 0, stream>>>(hbuf, bat, pool);
    k_pool_fin<<<(NB * CH + 255) / 256, 256, 0, stream>>>(pool, cnt, poolp);

    // ---- head MLP: out = relu(h@Wl0+bl0) @ Wl1 + bl1 ----
    k_gemm<CH, true, true, false, false, float, f16>
        <<<gRow, 256, 0, stream>>>(hbuf, Wl0, bl0, lbuf, nullptr, nullptr, CH);
    k_gemm<COUT, true, false, false, false, f16, float>
        <<<gRow, 256, 0, stream>>>(lbuf, Wl1, bl1, outp, nullptr, nullptr, CH);
}

// Round 6
// 1162.028 us; speedup vs baseline: 7.6630x; 1.2485x over previous
//
#include <hip/hip_runtime.h>
#include <hip/hip_fp16.h>

typedef __half f16;

#define NN   100000   // nodes
#define NE   1600000  // edges
#define CIN  256
#define CH   128
#define COUT 64
#define NB   64
#define NBLK 391      // ceil(NN/256)

// ---------------- diagnostics ----------------
__global__ void k_sentinel(float* __restrict__ out, int n, float val) {
    int i = blockIdx.x * 256 + threadIdx.x;
    if (i < n) out[i] = val;
}

// ---------------- setup kernels ----------------
__global__ void k_init(int* __restrict__ deg, float* __restrict__ pool,
                       float* __restrict__ cnt) {
    int i = blockIdx.x * 256 + threadIdx.x;
    if (i < NN) deg[i] = 0;
    if (i < NB * CH) pool[i] = 0.0f;
    if (i < NB) cnt[i] = 0.0f;
}

__global__ void k_deg(const int* __restrict__ dst, int* __restrict__ deg) {
    int e = blockIdx.x * 256 + threadIdx.x;
    if (e < NE) atomicAdd(&deg[dst[e]], 1);
}

// ---- hierarchical scan, phase 1: per-block inclusive scan + block sums ----
__global__ __launch_bounds__(256) void k_scan_blk(const int* __restrict__ deg,
                                                  int* __restrict__ rowptr,
                                                  int* __restrict__ bsum) {
    __shared__ int wsum[4];
    const int tid = threadIdx.x, lane = tid & 63, wv = tid >> 6;
    const int i = blockIdx.x * 256 + tid;
    int v = (i < NN) ? deg[i] : 0;
#pragma unroll
    for (int off = 1; off < 64; off <<= 1) {
        int t = __shfl_up(v, off);
        if (lane >= off) v += t;
    }
    if (lane == 63) wsum[wv] = v;
    __syncthreads();
    int add = 0;
    for (int w = 0; w < wv; ++w) add += wsum[w];
    int incl = v + add;
    if (i < NN) rowptr[i + 1] = incl;          // block-local inclusive
    if (tid == 255) bsum[blockIdx.x] = incl;   // block total
}

// ---- phase 2: single-block inclusive scan of NBLK block sums ----
__global__ __launch_bounds__(256) void k_scan_top(int* __restrict__ bsum) {
    __shared__ int wsum[4];
    __shared__ int carry_s;
    const int tid = threadIdx.x, lane = tid & 63, wv = tid >> 6;
    if (tid == 0) carry_s = 0;
    __syncthreads();
    for (int base = 0; base < NBLK; base += 256) {
        int i = base + tid;
        int v = (i < NBLK) ? bsum[i] : 0;
#pragma unroll
        for (int off = 1; off < 64; off <<= 1) {
            int t = __shfl_up(v, off);
            if (lane >= off) v += t;
        }
        if (lane == 63) wsum[wv] = v;
        __syncthreads();
        int add = carry_s;
        for (int w = 0; w < wv; ++w) add += wsum[w];
        int incl = v + add;
        if (i < NBLK) bsum[i] = incl;          // in-place inclusive
        __syncthreads();
        if (tid == 255) carry_s = incl;
        __syncthreads();
    }
}

// ---- phase 3: add block offsets; finalize rowptr[0] ----
__global__ __launch_bounds__(256) void k_scan_add(int* __restrict__ rowptr,
                                                  const int* __restrict__ bsum) {
    const int b = blockIdx.x;
    const int i = b * 256 + threadIdx.x;
    int off = (b > 0) ? bsum[b - 1] : 0;
    if (i < NN) rowptr[i + 1] += off;
    if (i == 0) rowptr[0] = 0;
}

// dinv = rsqrt(deg+1);  cursor = rowptr (fill cursors)
__global__ void k_dinv_cur(const int* __restrict__ deg, const int* __restrict__ rowptr,
                           float* __restrict__ dinv, int* __restrict__ cursor) {
    int i = blockIdx.x * 256 + threadIdx.x;
    if (i < NN) {
        dinv[i] = rsqrtf((float)deg[i] + 1.0f);
        cursor[i] = rowptr[i];
    }
}

__global__ void k_fill(const int* __restrict__ src, const int* __restrict__ dst,
                       int* __restrict__ cursor, int* __restrict__ csr) {
    int e = blockIdx.x * 256 + threadIdx.x;
    if (e < NE) {
        int pos = atomicAdd(&cursor[dst[e]], 1);
        csr[pos] = src[e];
    }
}

// ---------------- GEMM: C[N,M] = A[N,K] @ W[K,M] ----------------
// 256 threads, 64 rows x M cols per block, K staged in 64-chunks in LDS.
// DUAL: writes ONLY C2[row,col] = (f16)((v)*dinv[row])  (pre-scaled message).
template <int M, bool BIAS, bool RELU, bool ACCUM, bool DUAL, typename TA, typename TO>
__global__ __launch_bounds__(256) void k_gemm(const TA* __restrict__ A,
                                              const float* __restrict__ W,
                                              const float* __restrict__ bias,
                                              TO* __restrict__ C,
                                              f16* __restrict__ C2,
                                              const float* __restrict__ dinv,
                                              int K) {
    constexpr int KC = 64, BR = 64;
    constexpr int CG = M / 4;        // column groups (4 cols each)
    constexpr int TYN = 256 / CG;    // row groups
    constexpr int RPT = BR / TYN;    // rows per thread
    __shared__ float Wl[KC * M];
    __shared__ float Al[BR * (KC + 1)];
    const int tid = threadIdx.x;
    const int tx = tid % CG, ty = tid / CG;
    const int rb = blockIdx.x * BR;

    float acc[RPT][4];
#pragma unroll
    for (int r = 0; r < RPT; ++r)
        acc[r][0] = acc[r][1] = acc[r][2] = acc[r][3] = 0.0f;

    for (int k0 = 0; k0 < K; k0 += KC) {
        __syncthreads();
        for (int idx = tid; idx < KC * M; idx += 256)
            Wl[idx] = W[(size_t)(k0 + idx / M) * M + (idx % M)];
        for (int idx = tid; idx < BR * KC; idx += 256) {
            int kk = idx % KC, r = idx / KC;
            int row = rb + r;
            Al[r * (KC + 1) + kk] =
                (row < NN) ? (float)A[(size_t)row * K + k0 + kk] : 0.0f;
        }
        __syncthreads();
#pragma unroll 4
        for (int kk = 0; kk < KC; ++kk) {
            const float4 w = *(const float4*)&Wl[kk * M + tx * 4];
#pragma unroll
            for (int r = 0; r < RPT; ++r) {
                float a = Al[(ty * RPT + r) * (KC + 1) + kk];
                acc[r][0] += a * w.x;
                acc[r][1] += a * w.y;
                acc[r][2] += a * w.z;
                acc[r][3] += a * w.w;
            }
        }
    }
#pragma unroll
    for (int r = 0; r < RPT; ++r) {
        int row = rb + ty * RPT + r;
        if (row >= NN) continue;
        size_t base = (size_t)row * M + tx * 4;
        float sl = DUAL ? dinv[row] : 0.0f;
#pragma unroll
        for (int c = 0; c < 4; ++c) {
            float v = acc[r][c];
            if (BIAS) v += bias[tx * 4 + c];
            if (RELU) v = fmaxf(v, 0.0f);
            if (DUAL) {
                C2[base + c] = (f16)(v * sl);     // pre-scaled message
            } else {
                if (ACCUM) v += (float)C[base + c];
                C[base + c] = (TO)v;
            }
        }
    }
}

// ---------------- CSR gather + BN + ReLU ----------------
// one wave per dst node; lane holds features [2*lane, 2*lane+1]
// h[d] = relu(( dinv[d]*(linscaled[d] + sum_edges linscaled[src]) + b )*g' + be)
__global__ __launch_bounds__(256) void k_gather(const int* __restrict__ rowptr,
                                                const int* __restrict__ csr,
                                                const float* __restrict__ dinv,
                                                const f16* __restrict__ lin,
                                                float* __restrict__ h,
                                                const float* __restrict__ b,
                                                const float* __restrict__ g,
                                                const float* __restrict__ be) {
    const int gw = (blockIdx.x * 256 + threadIdx.x) >> 6;   // dst node
    const int lane = threadIdx.x & 63;
    if (gw >= NN) return;
    const __half2* lp = (const __half2*)lin;
    const int start = rowptr[gw], end = rowptr[gw + 1];

    float2 acc = __half22float2(lp[(size_t)gw * 64 + lane]);  // self term
    int j = start;
    for (; j + 3 < end; j += 4) {
        int s0 = csr[j], s1 = csr[j + 1], s2 = csr[j + 2], s3 = csr[j + 3];
        float2 v0 = __half22float2(lp[(size_t)s0 * 64 + lane]);
        float2 v1 = __half22float2(lp[(size_t)s1 * 64 + lane]);
        float2 v2 = __half22float2(lp[(size_t)s2 * 64 + lane]);
        float2 v3 = __half22float2(lp[(size_t)s3 * 64 + lane]);
        acc.x += v0.x + v1.x + v2.x + v3.x;
        acc.y += v0.y + v1.y + v2.y + v3.y;
    }
    for (; j < end; ++j) {
        int s = csr[j];
        float2 v = __half22float2(lp[(size_t)s * 64 + lane]);
        acc.x += v.x;
        acc.y += v.y;
    }
    const float inv_sqrt = 0.99999500003749968f;  // 1/sqrt(1+1e-5)
    float dv = dinv[gw];
    int f = lane * 2;
    float2 bb = *(const float2*)&b[f];
    float2 gg = *(const float2*)&g[f];
    float2 ee = *(const float2*)&be[f];
    float t0 = (acc.x * dv + bb.x) * (gg.x * inv_sqrt) + ee.x;
    float t1 = (acc.y * dv + bb.y) * (gg.y * inv_sqrt) + ee.y;
    ((float2*)h)[(size_t)gw * 64 + lane] = make_float2(fmaxf(t0, 0.0f), fmaxf(t1, 0.0f));
}

// ---------------- pooling ----------------
__global__ void k_count(const int* __restrict__ batch, float* __restrict__ cnt) {
    __shared__ float hist[NB];
    int tid = threadIdx.x;
    if (tid < NB) hist[tid] = 0.0f;
    __syncthreads();
    int n = blockIdx.x * 256 + tid;
    if (n < NN) atomicAdd(&hist[batch[n]], 1.0f);
    __syncthreads();
    if (tid < NB && hist[tid] != 0.0f) atomicAdd(&cnt[tid], hist[tid]);
}

// 128 threads (one per feature), 64 consecutive nodes; correct for any sorted batch
__global__ void k_pool(const float* __restrict__ h, const int* __restrict__ batch,
                       float* __restrict__ pool) {
    int n0 = blockIdx.x * 64;
    int j = threadIdx.x;
    int cur = batch[n0];
    float acc = 0.0f;
    int nend = (n0 + 64 < NN) ? n0 + 64 : NN;
    for (int n = n0; n < nend; ++n) {
        int b = batch[n];
        if (b != cur) {
            atomicAdd(&pool[cur * CH + j], acc);
            acc = 0.0f;
            cur = b;
        }
        acc += h[(size_t)n * CH + j];
    }
    atomicAdd(&pool[cur * CH + j], acc);
}

__global__ void k_pool_fin(const float* __restrict__ pool,
                           const float* __restrict__ cnt,
                           float* __restrict__ out) {
    int i = blockIdx.x * 256 + threadIdx.x;
    if (i < NB * CH) {
        float c = fmaxf(cnt[i / CH], 1.0f);
        out[i] = pool[i] / c;
    }
}

// ---------------- launch ----------------
extern "C" void kernel_launch(void* const* d_in, const int* in_sizes, int n_in,
                              void* d_out, int out_size, void* d_ws, size_t ws_size,
                              hipStream_t stream) {
    float* outp  = (float*)d_out;                  // [NN, COUT] f32
    float* poolp = outp + (size_t)NN * COUT;       // [NB, CH] f32

    // ---- workspace layout (~84.9 MB) ----
    const size_t HB = (size_t)NN * CH * 4;         // 51.2 MB f32 h
    const size_t LB = (size_t)NN * CH * 2;         // 25.6 MB f16 linscaled
    const size_t DV = (size_t)NN * 4;              // dinv
    const size_t RP = (size_t)(NN + 1) * 4;        // rowptr
    const size_t CU = (size_t)NN * 4;              // cursor
    const size_t CS = (size_t)NE * 4;              // csr
    const size_t DG = (size_t)NN * 4;              // deg
    const size_t BS = (size_t)NBLK * 4;            // block sums
    const size_t PL = (size_t)NB * CH * 4;
    const size_t CT = (size_t)NB * 4;
    const size_t need = HB + LB + DV + RP + CU + CS + DG + BS + PL + CT;
    if (ws_size < need) {
        k_sentinel<<<(out_size + 255) / 256, 256, 0, stream>>>(outp, out_size, 2000.0f);
        return;
    }
    char* p = (char*)d_ws;
    float* hbuf   = (float*)p;             p += HB;
    f16*   lbuf   = (f16*)p;               p += LB;
    float* dinv   = (float*)p;             p += DV;
    int*   rowptr = (int*)p;               p += RP;
    int*   cursor = (int*)p;               p += CU;
    int*   csr    = (int*)p;               p += CS;
    int*   deg    = (int*)p;               p += DG;
    int*   bsum   = (int*)p;               p += BS;
    float* pool   = (float*)p;             p += PL;
    float* cnt    = (float*)p;

    const float* x   = (const float*)d_in[0];
    const int*   ei  = (const int*)d_in[1];
    const int*   bat = (const int*)d_in[2];
    const float* W0 = (const float*)d_in[3],  *b0 = (const float*)d_in[4];
    const float* W1 = (const float*)d_in[5],  *b1 = (const float*)d_in[6];
    const float* W2 = (const float*)d_in[7],  *b2 = (const float*)d_in[8];
    const float* g0 = (const float*)d_in[9],  *be0 = (const float*)d_in[10];
    const float* g1 = (const float*)d_in[11], *be1 = (const float*)d_in[12];
    const float* g2 = (const float*)d_in[13], *be2 = (const float*)d_in[14];
    const float* Wres = (const float*)d_in[15], *bres = (const float*)d_in[16];
    const float* Wl0 = (const float*)d_in[17], *bl0 = (const float*)d_in[18];
    const float* Wl1 = (const float*)d_in[19], *bl1 = (const float*)d_in[20];

    const int* src = ei;
    const int* dst = ei + NE;

    const int gN   = NBLK;                        // 391
    const int gE   = (NE + 255) / 256;            // 6250
    const int gRow = (NN + 63) / 64;              // 1563
    const int gGat = (NN * 64) / 256;             // 25000 (exact)

    // ---- degrees + CSR build (hierarchical scan) ----
    k_init<<<gN, 256, 0, stream>>>(deg, pool, cnt);
    k_deg<<<gE, 256, 0, stream>>>(dst, deg);
    k_scan_blk<<<gN, 256, 0, stream>>>(deg, rowptr, bsum);
    k_scan_top<<<1, 256, 0, stream>>>(bsum);
    k_scan_add<<<gN, 256, 0, stream>>>(rowptr, bsum);
    k_dinv_cur<<<gN, 256, 0, stream>>>(deg, rowptr, dinv, cursor);
    k_fill<<<gE, 256, 0, stream>>>(src, dst, cursor, csr);

    // ---- layer 0: lbuf = f16((x@W0)*dinv[row]); gather+BN+ReLU -> hbuf ----
    k_gemm<CH, false, false, false, true, float, float>
        <<<gRow, 256, 0, stream>>>(x, W0, nullptr, nullptr, lbuf, dinv, CIN);
    k_gather<<<gGat, 256, 0, stream>>>(rowptr, csr, dinv, lbuf, hbuf, b0, g0, be0);
    // residual: h += x @ Wres + bres
    k_gemm<CH, true, false, true, false, float, float>
        <<<gRow, 256, 0, stream>>>(x, Wres, bres, hbuf, nullptr, nullptr, CIN);

    // ---- layer 1 ----
    k_gemm<CH, false, false, false, true, float, float>
        <<<gRow, 256, 0, stream>>>(hbuf, W1, nullptr, nullptr, lbuf, dinv, CH);
    k_gather<<<gGat, 256, 0, stream>>>(rowptr, csr, dinv, lbuf, hbuf, b1, g1, be1);

    // ---- layer 2 ----
    k_gemm<CH, false, false, false, true, float, float>
        <<<gRow, 256, 0, stream>>>(hbuf, W2, nullptr, nullptr, lbuf, dinv, CH);
    k_gather<<<gGat, 256, 0, stream>>>(rowptr, csr, dinv, lbuf, hbuf, b2, g2, be2);

    // ---- mean pool over graphs (final h) ----
    k_count<<<gN, 256, 0, stream>>>(bat, cnt);
    k_pool<<<gRow, 128, 0, stream>>>(hbuf, bat, pool);
    k_pool_fin<<<(NB * CH + 255) / 256, 256, 0, stream>>>(pool, cnt, poolp);

    // ---- head MLP: out = relu(h@Wl0+bl0) @ Wl1 + bl1 ----
    k_gemm<CH, true, true, false, false, float, f16>
        <<<gRow, 256, 0, stream>>>(hbuf, Wl0, bl0, lbuf, nullptr, nullptr, CH);
    k_gemm<COUT, true, false, false, false, f16, float>
        <<<gRow, 256, 0, stream>>>(lbuf, Wl1, bl1, outp, nullptr, nullptr, CH);
}

// Round 7
// 823.812 us; speedup vs baseline: 10.8091x; 1.4106x over previous
//
#include <hip/hip_runtime.h>
#include <hip/hip_fp16.h>

typedef __half f16;
typedef _Float16 half8 __attribute__((ext_vector_type(8)));
typedef float floatx4 __attribute__((ext_vector_type(4)));

#define NN   100000   // nodes
#define NE   1600000  // edges
#define CIN  256
#define CH   128
#define COUT 64
#define NB   64
#define NBLK 391      // ceil(NN/256)

// ---------------- diagnostics ----------------
__global__ void k_sentinel(float* __restrict__ out, int n, float val) {
    int i = blockIdx.x * 256 + threadIdx.x;
    if (i < n) out[i] = val;
}

// ---------------- setup kernels ----------------
__global__ void k_init(int* __restrict__ deg, float* __restrict__ pool,
                       float* __restrict__ cnt) {
    int i = blockIdx.x * 256 + threadIdx.x;
    if (i < NN) deg[i] = 0;
    if (i < NB * CH) pool[i] = 0.0f;
    if (i < NB) cnt[i] = 0.0f;
}

__global__ void k_deg(const int* __restrict__ dst, int* __restrict__ deg) {
    int e = blockIdx.x * 256 + threadIdx.x;
    if (e < NE) atomicAdd(&deg[dst[e]], 1);
}

// ---- hierarchical scan ----
__global__ __launch_bounds__(256) void k_scan_blk(const int* __restrict__ deg,
                                                  int* __restrict__ rowptr,
                                                  int* __restrict__ bsum) {
    __shared__ int wsum[4];
    const int tid = threadIdx.x, lane = tid & 63, wv = tid >> 6;
    const int i = blockIdx.x * 256 + tid;
    int v = (i < NN) ? deg[i] : 0;
#pragma unroll
    for (int off = 1; off < 64; off <<= 1) {
        int t = __shfl_up(v, off);
        if (lane >= off) v += t;
    }
    if (lane == 63) wsum[wv] = v;
    __syncthreads();
    int add = 0;
    for (int w = 0; w < wv; ++w) add += wsum[w];
    int incl = v + add;
    if (i < NN) rowptr[i + 1] = incl;
    if (tid == 255) bsum[blockIdx.x] = incl;
}

__global__ __launch_bounds__(256) void k_scan_top(int* __restrict__ bsum) {
    __shared__ int wsum[4];
    __shared__ int carry_s;
    const int tid = threadIdx.x, lane = tid & 63, wv = tid >> 6;
    if (tid == 0) carry_s = 0;
    __syncthreads();
    for (int base = 0; base < NBLK; base += 256) {
        int i = base + tid;
        int v = (i < NBLK) ? bsum[i] : 0;
#pragma unroll
        for (int off = 1; off < 64; off <<= 1) {
            int t = __shfl_up(v, off);
            if (lane >= off) v += t;
        }
        if (lane == 63) wsum[wv] = v;
        __syncthreads();
        int add = carry_s;
        for (int w = 0; w < wv; ++w) add += wsum[w];
        int incl = v + add;
        if (i < NBLK) bsum[i] = incl;
        __syncthreads();
        if (tid == 255) carry_s = incl;
        __syncthreads();
    }
}

__global__ __launch_bounds__(256) void k_scan_add(int* __restrict__ rowptr,
                                                  const int* __restrict__ bsum) {
    const int b = blockIdx.x;
    const int i = b * 256 + threadIdx.x;
    int off = (b > 0) ? bsum[b - 1] : 0;
    if (i < NN) rowptr[i + 1] += off;
    if (i == 0) rowptr[0] = 0;
}

__global__ void k_dinv_cur(const int* __restrict__ deg, const int* __restrict__ rowptr,
                           float* __restrict__ dinv, int* __restrict__ cursor) {
    int i = blockIdx.x * 256 + threadIdx.x;
    if (i < NN) {
        dinv[i] = rsqrtf((float)deg[i] + 1.0f);
        cursor[i] = rowptr[i];
    }
}

__global__ void k_fill(const int* __restrict__ src, const int* __restrict__ dst,
                       int* __restrict__ cursor, int* __restrict__ csr) {
    int e = blockIdx.x * 256 + threadIdx.x;
    if (e < NE) {
        int pos = atomicAdd(&cursor[dst[e]], 1);
        csr[pos] = src[e];
    }
}

// ---------------- MFMA GEMM ----------------
// C[N,M] = A[N,K] @ W[K,M].  Block: 256 thr (4 waves), 64 rows x M cols.
// 16x16x32 f16 MFMA, f32 accum. A-tile 64x32 and W-tile [n][k] staged in LDS.
// EPI 0: M=256, W=[W0|Wres] (two ptrs): col<128 -> lout=f16(v*dinv[row]);
//        col>=128 -> rout=f16(v+bias[col-128])
// EPI 1: lout = f16(v*dinv[row])
// EPI 2: lout = f16(relu(v+bias[col]))
// EPI 3: fout[row*M+col] = v + bias[col]   (f32)
template <int M, int EPI, bool AF32>
__global__ __launch_bounds__(256) void k_mfma(const void* __restrict__ Av,
                                              const float* __restrict__ W,
                                              const float* __restrict__ Wb,
                                              const float* __restrict__ bias,
                                              const float* __restrict__ dinv,
                                              f16* __restrict__ lout,
                                              f16* __restrict__ rout,
                                              float* __restrict__ fout,
                                              int K) {
    constexpr int KC = 32, APAD = 40, WPAD = 40;
    constexpr int NT = M / 16;
    __shared__ _Float16 Al[64 * APAD];
    __shared__ _Float16 Wl[M * WPAD];
    const int tid = threadIdx.x;
    const int wave = tid >> 6, lane = tid & 63;
    const int fm = lane & 15, g = lane >> 4;
    const int rb = blockIdx.x * 64;

    floatx4 acc[NT];
#pragma unroll
    for (int t = 0; t < NT; ++t)
#pragma unroll
        for (int r = 0; r < 4; ++r) acc[t][r] = 0.0f;

    const int arow = tid >> 2;            // 0..63
    const int koff = (tid & 3) * 8;

    for (int k0 = 0; k0 < K; k0 += KC) {
        __syncthreads();
        // stage A 64x32 -> f16
        {
            int grow = rb + arow;
            half8 av;
            if (grow < NN) {
                if (AF32) {
                    const float* ap = (const float*)Av + (size_t)grow * K + k0 + koff;
                    float4 v0 = *(const float4*)ap;
                    float4 v1 = *(const float4*)(ap + 4);
                    av[0] = (_Float16)v0.x; av[1] = (_Float16)v0.y;
                    av[2] = (_Float16)v0.z; av[3] = (_Float16)v0.w;
                    av[4] = (_Float16)v1.x; av[5] = (_Float16)v1.y;
                    av[6] = (_Float16)v1.z; av[7] = (_Float16)v1.w;
                } else {
                    av = *(const half8*)((const _Float16*)Av + (size_t)grow * K + k0 + koff);
                }
            } else {
#pragma unroll
                for (int i = 0; i < 8; ++i) av[i] = (_Float16)0.0f;
            }
            *(half8*)&Al[arow * APAD + koff] = av;
        }
        // stage W 32xM transposed -> Wl[n][k]
        for (int idx = tid; idx < KC * M; idx += 256) {
            int k = idx / M, n = idx % M;
            float wv;
            if (EPI == 0) {
                wv = (n < 128) ? W[(size_t)(k0 + k) * 128 + n]
                               : Wb[(size_t)(k0 + k) * 128 + (n - 128)];
            } else {
                wv = W[(size_t)(k0 + k) * M + n];
            }
            Wl[n * WPAD + k] = (_Float16)wv;
        }
        __syncthreads();
        half8 afrag = *(const half8*)&Al[(wave * 16 + fm) * APAD + g * 8];
#pragma unroll
        for (int t = 0; t < NT; ++t) {
            half8 bfrag = *(const half8*)&Wl[(t * 16 + fm) * WPAD + g * 8];
            acc[t] = __builtin_amdgcn_mfma_f32_16x16x32_f16(afrag, bfrag, acc[t], 0, 0, 0);
        }
    }
    // epilogue: row = rb + wave*16 + g*4 + r, col = t*16 + fm
    const int rloc = wave * 16 + g * 4;
#pragma unroll
    for (int t = 0; t < NT; ++t) {
        int col = t * 16 + fm;
#pragma unroll
        for (int r = 0; r < 4; ++r) {
            int row = rb + rloc + r;
            if (row >= NN) continue;
            float v = acc[t][r];
            if (EPI == 0) {
                if (col < 128) lout[(size_t)row * 128 + col] = (f16)(v * dinv[row]);
                else           rout[(size_t)row * 128 + (col - 128)] = (f16)(v + bias[col - 128]);
            } else if (EPI == 1) {
                lout[(size_t)row * M + col] = (f16)(v * dinv[row]);
            } else if (EPI == 2) {
                lout[(size_t)row * M + col] = (f16)fmaxf(v + bias[col], 0.0f);
            } else {
                fout[(size_t)row * M + col] = v + bias[col];
            }
        }
    }
}

// ---------------- CSR gather + BN + ReLU (+residual) ----------------
// one wave per dst node; lane holds features [2*lane, 2*lane+1]; h out f16
template <bool RES>
__global__ __launch_bounds__(256) void k_gather(const int* __restrict__ rowptr,
                                                const int* __restrict__ csr,
                                                const float* __restrict__ dinv,
                                                const f16* __restrict__ lin,
                                                const f16* __restrict__ res,
                                                f16* __restrict__ h,
                                                const float* __restrict__ b,
                                                const float* __restrict__ g,
                                                const float* __restrict__ be) {
    const int gw = (blockIdx.x * 256 + threadIdx.x) >> 6;   // dst node
    const int lane = threadIdx.x & 63;
    if (gw >= NN) return;
    const __half2* lp = (const __half2*)lin;
    const int start = rowptr[gw], end = rowptr[gw + 1];

    float2 acc = __half22float2(lp[(size_t)gw * 64 + lane]);  // self term
    int j = start;
    for (; j + 3 < end; j += 4) {
        int s0 = csr[j], s1 = csr[j + 1], s2 = csr[j + 2], s3 = csr[j + 3];
        float2 v0 = __half22float2(lp[(size_t)s0 * 64 + lane]);
        float2 v1 = __half22float2(lp[(size_t)s1 * 64 + lane]);
        float2 v2 = __half22float2(lp[(size_t)s2 * 64 + lane]);
        float2 v3 = __half22float2(lp[(size_t)s3 * 64 + lane]);
        acc.x += v0.x + v1.x + v2.x + v3.x;
        acc.y += v0.y + v1.y + v2.y + v3.y;
    }
    for (; j < end; ++j) {
        int s = csr[j];
        float2 v = __half22float2(lp[(size_t)s * 64 + lane]);
        acc.x += v.x;
        acc.y += v.y;
    }
    const float inv_sqrt = 0.99999500003749968f;  // 1/sqrt(1+1e-5)
    float dv = dinv[gw];
    int f = lane * 2;
    float2 bb = *(const float2*)&b[f];
    float2 gg = *(const float2*)&g[f];
    float2 ee = *(const float2*)&be[f];
    float t0 = fmaxf((acc.x * dv + bb.x) * (gg.x * inv_sqrt) + ee.x, 0.0f);
    float t1 = fmaxf((acc.y * dv + bb.y) * (gg.y * inv_sqrt) + ee.y, 0.0f);
    if (RES) {
        float2 rv = __half22float2(((const __half2*)res)[(size_t)gw * 64 + lane]);
        t0 += rv.x;
        t1 += rv.y;
    }
    ((__half2*)h)[(size_t)gw * 64 + lane] = __floats2half2_rn(t0, t1);
}

// ---------------- pooling ----------------
__global__ void k_count(const int* __restrict__ batch, float* __restrict__ cnt) {
    __shared__ float hist[NB];
    int tid = threadIdx.x;
    if (tid < NB) hist[tid] = 0.0f;
    __syncthreads();
    int n = blockIdx.x * 256 + tid;
    if (n < NN) atomicAdd(&hist[batch[n]], 1.0f);
    __syncthreads();
    if (tid < NB && hist[tid] != 0.0f) atomicAdd(&cnt[tid], hist[tid]);
}

__global__ void k_pool(const f16* __restrict__ h, const int* __restrict__ batch,
                       float* __restrict__ pool) {
    int n0 = blockIdx.x * 64;
    int j = threadIdx.x;
    int cur = batch[n0];
    float acc = 0.0f;
    int nend = (n0 + 64 < NN) ? n0 + 64 : NN;
    for (int n = n0; n < nend; ++n) {
        int b = batch[n];
        if (b != cur) {
            atomicAdd(&pool[cur * CH + j], acc);
            acc = 0.0f;
            cur = b;
        }
        acc += (float)h[(size_t)n * CH + j];
    }
    atomicAdd(&pool[cur * CH + j], acc);
}

__global__ void k_pool_fin(const float* __restrict__ pool,
                           const float* __restrict__ cnt,
                           float* __restrict__ out) {
    int i = blockIdx.x * 256 + threadIdx.x;
    if (i < NB * CH) {
        float c = fmaxf(cnt[i / CH], 1.0f);
        out[i] = pool[i] / c;
    }
}

// ---------------- launch ----------------
extern "C" void kernel_launch(void* const* d_in, const int* in_sizes, int n_in,
                              void* d_out, int out_size, void* d_ws, size_t ws_size,
                              hipStream_t stream) {
    float* outp  = (float*)d_out;                  // [NN, COUT] f32
    float* poolp = outp + (size_t)NN * COUT;       // [NB, CH] f32

    // ---- workspace layout (~84.9 MB) ----
    const size_t HB = (size_t)NN * CH * 2;         // f16 h
    const size_t LB = (size_t)NN * CH * 2;         // f16 linscaled
    const size_t RB = (size_t)NN * CH * 2;         // f16 residual
    const size_t DV = (size_t)NN * 4;
    const size_t RP = (size_t)(NN + 1) * 4;
    const size_t CU = (size_t)NN * 4;
    const size_t CS = (size_t)NE * 4;
    const size_t DG = (size_t)NN * 4;
    const size_t BS = (size_t)((NBLK + 3) & ~3) * 4;
    const size_t PL = (size_t)NB * CH * 4;
    const size_t CT = (size_t)NB * 4;
    const size_t need = HB + LB + RB + DV + RP + CU + CS + DG + BS + PL + CT;
    if (ws_size < need) {
        k_sentinel<<<(out_size + 255) / 256, 256, 0, stream>>>(outp, out_size, 2000.0f);
        return;
    }
    char* p = (char*)d_ws;
    f16*   hbuf   = (f16*)p;               p += HB;
    f16*   lbuf   = (f16*)p;               p += LB;
    f16*   rbuf   = (f16*)p;               p += RB;
    float* dinv   = (float*)p;             p += DV;
    int*   rowptr = (int*)p;               p += RP;
    int*   cursor = (int*)p;               p += CU;
    int*   csr    = (int*)p;               p += CS;
    int*   deg    = (int*)p;               p += DG;
    int*   bsum   = (int*)p;               p += BS;
    float* pool   = (float*)p;             p += PL;
    float* cnt    = (float*)p;

    const float* x   = (const float*)d_in[0];
    const int*   ei  = (const int*)d_in[1];
    const int*   bat = (const int*)d_in[2];
    const float* W0 = (const float*)d_in[3];
    const float* W1 = (const float*)d_in[5],  *b1 = (const float*)d_in[6];
    const float* W2 = (const float*)d_in[7],  *b2 = (const float*)d_in[8];
    const float* b0 = (const float*)d_in[4];
    const float* g0 = (const float*)d_in[9],  *be0 = (const float*)d_in[10];
    const float* g1 = (const float*)d_in[11], *be1 = (const float*)d_in[12];
    const float* g2 = (const float*)d_in[13], *be2 = (const float*)d_in[14];
    const float* Wres = (const float*)d_in[15], *bres = (const float*)d_in[16];
    const float* Wl0 = (const float*)d_in[17], *bl0 = (const float*)d_in[18];
    const float* Wl1 = (const float*)d_in[19], *bl1 = (const float*)d_in[20];

    const int* src = ei;
    const int* dst = ei + NE;

    const int gN   = NBLK;                        // 391
    const int gE   = (NE + 255) / 256;            // 6250
    const int gRow = (NN + 63) / 64;              // 1563
    const int gGat = (NN * 64) / 256;             // 25000

    // ---- degrees + CSR build ----
    k_init<<<gN, 256, 0, stream>>>(deg, pool, cnt);
    k_deg<<<gE, 256, 0, stream>>>(dst, deg);
    k_scan_blk<<<gN, 256, 0, stream>>>(deg, rowptr, bsum);
    k_scan_top<<<1, 256, 0, stream>>>(bsum);
    k_scan_add<<<gN, 256, 0, stream>>>(rowptr, bsum);
    k_dinv_cur<<<gN, 256, 0, stream>>>(deg, rowptr, dinv, cursor);
    k_fill<<<gE, 256, 0, stream>>>(src, dst, cursor, csr);

    // ---- layer 0 fused with residual: one pass over x ----
    // lbuf = f16((x@W0)*dinv), rbuf = f16(x@Wres + bres)
    k_mfma<256, 0, true><<<gRow, 256, 0, stream>>>(x, W0, Wres, bres, dinv,
                                                   lbuf, rbuf, nullptr, CIN);
    k_gather<true><<<gGat, 256, 0, stream>>>(rowptr, csr, dinv, lbuf, rbuf, hbuf, b0, g0, be0);

    // ---- layer 1 ----
    k_mfma<128, 1, false><<<gRow, 256, 0, stream>>>(hbuf, W1, nullptr, nullptr, dinv,
                                                    lbuf, nullptr, nullptr, CH);
    k_gather<false><<<gGat, 256, 0, stream>>>(rowptr, csr, dinv, lbuf, nullptr, hbuf, b1, g1, be1);

    // ---- layer 2 ----
    k_mfma<128, 1, false><<<gRow, 256, 0, stream>>>(hbuf, W2, nullptr, nullptr, dinv,
                                                    lbuf, nullptr, nullptr, CH);
    k_gather<false><<<gGat, 256, 0, stream>>>(rowptr, csr, dinv, lbuf, nullptr, hbuf, b2, g2, be2);

    // ---- mean pool over graphs (final h) ----
    k_count<<<gN, 256, 0, stream>>>(bat, cnt);
    k_pool<<<gRow, 128, 0, stream>>>(hbuf, bat, pool);
    k_pool_fin<<<(NB * CH + 255) / 256, 256, 0, stream>>>(pool, cnt, poolp);

    // ---- head MLP ----
    k_mfma<128, 2, false><<<gRow, 256, 0, stream>>>(hbuf, Wl0, nullptr, bl0, nullptr,
                                                    lbuf, nullptr, nullptr, CH);
    k_mfma<64, 3, false><<<gRow, 256, 0, stream>>>(lbuf, Wl1, nullptr, bl1, nullptr,
                                                   nullptr, nullptr, outp, CH);
}

// Round 8
// 796.616 us; speedup vs baseline: 11.1781x; 1.0341x over previous
//
#include <hip/hip_runtime.h>
#include <hip/hip_fp16.h>

typedef __half f16;
typedef _Float16 half8 __attribute__((ext_vector_type(8)));
typedef float floatx4 __attribute__((ext_vector_type(4)));

#define NN   100000   // nodes
#define NE   1600000  // edges
#define CIN  256
#define CH   128
#define COUT 64
#define NB   64
#define NBLK 391      // ceil(NN/256)

// ---------------- diagnostics ----------------
__global__ void k_sentinel(float* __restrict__ out, int n, float val) {
    int i = blockIdx.x * 256 + threadIdx.x;
    if (i < n) out[i] = val;
}

// ---------------- setup kernels ----------------
__global__ void k_init(int* __restrict__ deg, float* __restrict__ pool,
                       float* __restrict__ cnt) {
    int i = blockIdx.x * 256 + threadIdx.x;
    if (i < NN) deg[i] = 0;
    if (i < NB * CH) pool[i] = 0.0f;
    if (i < NB) cnt[i] = 0.0f;
}

__global__ void k_deg(const int* __restrict__ dst, int* __restrict__ deg) {
    int e = blockIdx.x * 256 + threadIdx.x;
    if (e < NE) atomicAdd(&deg[dst[e]], 1);
}

// ---- hierarchical scan ----
__global__ __launch_bounds__(256) void k_scan_blk(const int* __restrict__ deg,
                                                  int* __restrict__ rowptr,
                                                  int* __restrict__ bsum) {
    __shared__ int wsum[4];
    const int tid = threadIdx.x, lane = tid & 63, wv = tid >> 6;
    const int i = blockIdx.x * 256 + tid;
    int v = (i < NN) ? deg[i] : 0;
#pragma unroll
    for (int off = 1; off < 64; off <<= 1) {
        int t = __shfl_up(v, off);
        if (lane >= off) v += t;
    }
    if (lane == 63) wsum[wv] = v;
    __syncthreads();
    int add = 0;
    for (int w = 0; w < wv; ++w) add += wsum[w];
    int incl = v + add;
    if (i < NN) rowptr[i + 1] = incl;
    if (tid == 255) bsum[blockIdx.x] = incl;
}

__global__ __launch_bounds__(256) void k_scan_top(int* __restrict__ bsum) {
    __shared__ int wsum[4];
    __shared__ int carry_s;
    const int tid = threadIdx.x, lane = tid & 63, wv = tid >> 6;
    if (tid == 0) carry_s = 0;
    __syncthreads();
    for (int base = 0; base < NBLK; base += 256) {
        int i = base + tid;
        int v = (i < NBLK) ? bsum[i] : 0;
#pragma unroll
        for (int off = 1; off < 64; off <<= 1) {
            int t = __shfl_up(v, off);
            if (lane >= off) v += t;
        }
        if (lane == 63) wsum[wv] = v;
        __syncthreads();
        int add = carry_s;
        for (int w = 0; w < wv; ++w) add += wsum[w];
        int incl = v + add;
        if (i < NBLK) bsum[i] = incl;
        __syncthreads();
        if (tid == 255) carry_s = incl;
        __syncthreads();
    }
}

__global__ __launch_bounds__(256) void k_scan_add(int* __restrict__ rowptr,
                                                  const int* __restrict__ bsum) {
    const int b = blockIdx.x;
    const int i = b * 256 + threadIdx.x;
    int off = (b > 0) ? bsum[b - 1] : 0;
    if (i < NN) rowptr[i + 1] += off;
    if (i == 0) rowptr[0] = 0;
}

__global__ void k_dinv_cur(const int* __restrict__ deg, const int* __restrict__ rowptr,
                           float* __restrict__ dinv, int* __restrict__ cursor) {
    int i = blockIdx.x * 256 + threadIdx.x;
    if (i < NN) {
        dinv[i] = rsqrtf((float)deg[i] + 1.0f);
        cursor[i] = rowptr[i];
    }
}

__global__ void k_fill(const int* __restrict__ src, const int* __restrict__ dst,
                       int* __restrict__ cursor, int* __restrict__ csr) {
    int e = blockIdx.x * 256 + threadIdx.x;
    if (e < NE) {
        int pos = atomicAdd(&cursor[dst[e]], 1);
        csr[pos] = src[e];
    }
}

// ---------------- weight -> f16 fragment-major conversion ----------------
// WF[(kt*(M/16) + t)*64 + lane] = half8 {W[(kt*32 + (lane>>4)*8 + j)*M + t*16 + (lane&15)]}
// Frag ranges: F0 4096 | Fres 4096 | F1 2048 | F2 2048 | Fl0 2048 | Fl1 1024
__global__ __launch_bounds__(256) void k_wconv(
        const float* __restrict__ W0, const float* __restrict__ Wres,
        const float* __restrict__ W1, const float* __restrict__ W2,
        const float* __restrict__ Wl0, const float* __restrict__ Wl1,
        half8* __restrict__ F0, half8* __restrict__ Fres,
        half8* __restrict__ F1, half8* __restrict__ F2,
        half8* __restrict__ Fl0, half8* __restrict__ Fl1) {
    int f = blockIdx.x * 256 + threadIdx.x;
    const float* W; half8* F; int M, base;
    if      (f <  4096) { W = W0;   F = F0;   M = 128; base = 0; }
    else if (f <  8192) { W = Wres; F = Fres; M = 128; base = 4096; }
    else if (f < 10240) { W = W1;   F = F1;   M = 128; base = 8192; }
    else if (f < 12288) { W = W2;   F = F2;   M = 128; base = 10240; }
    else if (f < 14336) { W = Wl0;  F = Fl0;  M = 128; base = 12288; }
    else if (f < 15360) { W = Wl1;  F = Fl1;  M = 64;  base = 14336; }
    else return;
    int fl = f - base;
    int lane = fl & 63, fm = lane & 15, g = lane >> 4;
    int rest = fl >> 6;
    int nt = M / 16;
    int t = rest % nt, kt = rest / nt;
    half8 v;
#pragma unroll
    for (int j = 0; j < 8; ++j)
        v[j] = (_Float16)W[(size_t)(kt * 32 + g * 8 + j) * M + t * 16 + fm];
    F[fl] = v;
}

// ---------------- MFMA GEMM ----------------
// C[N,M] = A[N,K] @ W[K,M].  Block: 256 thr (4 waves), 64 rows x M cols.
// B-fragments read directly from pre-converted fragment-major WF (L2-resident).
// LDS holds only the 64x32 A tile.
// EPI 0: M=256, frags: t<8 -> WF (W0), t>=8 -> WFb (Wres):
//        col<128 -> lout=f16(v*dinv[row]); col>=128 -> rout=f16(v+bias[col-128])
// EPI 1: lout = f16(v*dinv[row])
// EPI 2: lout = f16(relu(v+bias[col]))
// EPI 3: fout[row*M+col] = v + bias[col]   (f32)
template <int M, int EPI, bool AF32>
__global__ __launch_bounds__(256) void k_mfma(const void* __restrict__ Av,
                                              const half8* __restrict__ WF,
                                              const half8* __restrict__ WFb,
                                              const float* __restrict__ bias,
                                              const float* __restrict__ dinv,
                                              f16* __restrict__ lout,
                                              f16* __restrict__ rout,
                                              float* __restrict__ fout,
                                              int K) {
    constexpr int KC = 32, APAD = 40;
    constexpr int NT = M / 16;
    __shared__ _Float16 Al[64 * APAD];
    const int tid = threadIdx.x;
    const int wave = tid >> 6, lane = tid & 63;
    const int fm = lane & 15, g = lane >> 4;
    const int rb = blockIdx.x * 64;

    floatx4 acc[NT];
#pragma unroll
    for (int t = 0; t < NT; ++t)
#pragma unroll
        for (int r = 0; r < 4; ++r) acc[t][r] = 0.0f;

    const int arow = tid >> 2;            // 0..63
    const int koff = (tid & 3) * 8;

    for (int k0 = 0, kt = 0; k0 < K; k0 += KC, ++kt) {
        __syncthreads();
        // stage A 64x32 -> f16 in LDS
        {
            int grow = rb + arow;
            half8 av;
            if (grow < NN) {
                if (AF32) {
                    const float* ap = (const float*)Av + (size_t)grow * K + k0 + koff;
                    float4 v0 = *(const float4*)ap;
                    float4 v1 = *(const float4*)(ap + 4);
                    av[0] = (_Float16)v0.x; av[1] = (_Float16)v0.y;
                    av[2] = (_Float16)v0.z; av[3] = (_Float16)v0.w;
                    av[4] = (_Float16)v1.x; av[5] = (_Float16)v1.y;
                    av[6] = (_Float16)v1.z; av[7] = (_Float16)v1.w;
                } else {
                    av = *(const half8*)((const _Float16*)Av + (size_t)grow * K + k0 + koff);
                }
            } else {
#pragma unroll
                for (int i = 0; i < 8; ++i) av[i] = (_Float16)0.0f;
            }
            *(half8*)&Al[arow * APAD + koff] = av;
        }
        __syncthreads();
        half8 afrag = *(const half8*)&Al[(wave * 16 + fm) * APAD + g * 8];
#pragma unroll
        for (int t = 0; t < NT; ++t) {
            half8 bfrag;
            if (EPI == 0) {
                bfrag = (t < 8) ? WF[((size_t)kt * 8 + t) * 64 + lane]
                                : WFb[((size_t)kt * 8 + (t - 8)) * 64 + lane];
            } else {
                bfrag = WF[((size_t)kt * NT + t) * 64 + lane];
            }
            acc[t] = __builtin_amdgcn_mfma_f32_16x16x32_f16(afrag, bfrag, acc[t], 0, 0, 0);
        }
    }
    // epilogue: row = rb + wave*16 + g*4 + r, col = t*16 + fm
    const int rloc = wave * 16 + g * 4;
#pragma unroll
    for (int t = 0; t < NT; ++t) {
        int col = t * 16 + fm;
#pragma unroll
        for (int r = 0; r < 4; ++r) {
            int row = rb + rloc + r;
            if (row >= NN) continue;
            float v = acc[t][r];
            if (EPI == 0) {
                if (col < 128) lout[(size_t)row * 128 + col] = (f16)(v * dinv[row]);
                else           rout[(size_t)row * 128 + (col - 128)] = (f16)(v + bias[col - 128]);
            } else if (EPI == 1) {
                lout[(size_t)row * M + col] = (f16)(v * dinv[row]);
            } else if (EPI == 2) {
                lout[(size_t)row * M + col] = (f16)fmaxf(v + bias[col], 0.0f);
            } else {
                fout[(size_t)row * M + col] = v + bias[col];
            }
        }
    }
}

// ---------------- CSR gather + BN + ReLU (+residual) ----------------
// one wave per dst node; lane holds features [2*lane, 2*lane+1]; h out f16
template <bool RES>
__global__ __launch_bounds__(256) void k_gather(const int* __restrict__ rowptr,
                                                const int* __restrict__ csr,
                                                const float* __restrict__ dinv,
                                                const f16* __restrict__ lin,
                                                const f16* __restrict__ res,
                                                f16* __restrict__ h,
                                                const float* __restrict__ b,
                                                const float* __restrict__ g,
                                                const float* __restrict__ be) {
    const int gw = (blockIdx.x * 256 + threadIdx.x) >> 6;   // dst node
    const int lane = threadIdx.x & 63;
    if (gw >= NN) return;
    const __half2* lp = (const __half2*)lin;
    const int start = rowptr[gw], end = rowptr[gw + 1];

    float2 acc = __half22float2(lp[(size_t)gw * 64 + lane]);  // self term
    int j = start;
    for (; j + 3 < end; j += 4) {
        int s0 = csr[j], s1 = csr[j + 1], s2 = csr[j + 2], s3 = csr[j + 3];
        float2 v0 = __half22float2(lp[(size_t)s0 * 64 + lane]);
        float2 v1 = __half22float2(lp[(size_t)s1 * 64 + lane]);
        float2 v2 = __half22float2(lp[(size_t)s2 * 64 + lane]);
        float2 v3 = __half22float2(lp[(size_t)s3 * 64 + lane]);
        acc.x += v0.x + v1.x + v2.x + v3.x;
        acc.y += v0.y + v1.y + v2.y + v3.y;
    }
    for (; j < end; ++j) {
        int s = csr[j];
        float2 v = __half22float2(lp[(size_t)s * 64 + lane]);
        acc.x += v.x;
        acc.y += v.y;
    }
    const float inv_sqrt = 0.99999500003749968f;  // 1/sqrt(1+1e-5)
    float dv = dinv[gw];
    int f = lane * 2;
    float2 bb = *(const float2*)&b[f];
    float2 gg = *(const float2*)&g[f];
    float2 ee = *(const float2*)&be[f];
    float t0 = fmaxf((acc.x * dv + bb.x) * (gg.x * inv_sqrt) + ee.x, 0.0f);
    float t1 = fmaxf((acc.y * dv + bb.y) * (gg.y * inv_sqrt) + ee.y, 0.0f);
    if (RES) {
        float2 rv = __half22float2(((const __half2*)res)[(size_t)gw * 64 + lane]);
        t0 += rv.x;
        t1 += rv.y;
    }
    ((__half2*)h)[(size_t)gw * 64 + lane] = __floats2half2_rn(t0, t1);
}

// ---------------- pooling ----------------
__global__ void k_count(const int* __restrict__ batch, float* __restrict__ cnt) {
    __shared__ float hist[NB];
    int tid = threadIdx.x;
    if (tid < NB) hist[tid] = 0.0f;
    __syncthreads();
    int n = blockIdx.x * 256 + tid;
    if (n < NN) atomicAdd(&hist[batch[n]], 1.0f);
    __syncthreads();
    if (tid < NB && hist[tid] != 0.0f) atomicAdd(&cnt[tid], hist[tid]);
}

__global__ void k_pool(const f16* __restrict__ h, const int* __restrict__ batch,
                       float* __restrict__ pool) {
    int n0 = blockIdx.x * 64;
    int j = threadIdx.x;
    int cur = batch[n0];
    float acc = 0.0f;
    int nend = (n0 + 64 < NN) ? n0 + 64 : NN;
    for (int n = n0; n < nend; ++n) {
        int b = batch[n];
        if (b != cur) {
            atomicAdd(&pool[cur * CH + j], acc);
            acc = 0.0f;
            cur = b;
        }
        acc += (float)h[(size_t)n * CH + j];
    }
    atomicAdd(&pool[cur * CH + j], acc);
}

__global__ void k_pool_fin(const float* __restrict__ pool,
                           const float* __restrict__ cnt,
                           float* __restrict__ out) {
    int i = blockIdx.x * 256 + threadIdx.x;
    if (i < NB * CH) {
        float c = fmaxf(cnt[i / CH], 1.0f);
        out[i] = pool[i] / c;
    }
}

// ---------------- launch ----------------
extern "C" void kernel_launch(void* const* d_in, const int* in_sizes, int n_in,
                              void* d_out, int out_size, void* d_ws, size_t ws_size,
                              hipStream_t stream) {
    float* outp  = (float*)d_out;                  // [NN, COUT] f32
    float* poolp = outp + (size_t)NN * COUT;       // [NB, CH] f32

    // ---- workspace layout (~34 MB + 240 KB frags) ----
    const size_t HB = (size_t)NN * CH * 2;         // f16 h
    const size_t LB = (size_t)NN * CH * 2;         // f16 linscaled
    const size_t RB = (size_t)NN * CH * 2;         // f16 residual
    const size_t DV = (size_t)NN * 4;
    const size_t RP = (size_t)(NN + 1) * 4;
    const size_t CU = (size_t)NN * 4;
    const size_t CS = (size_t)NE * 4;
    const size_t DG = (size_t)NN * 4;
    const size_t BS = (size_t)((NBLK + 3) & ~3) * 4;
    const size_t PL = (size_t)NB * CH * 4;
    const size_t CT = (size_t)NB * 4;
    const size_t F0B = 4096 * 16, F1B = 2048 * 16, FLB = 1024 * 16;
    const size_t need = HB + LB + RB + DV + RP + CU + CS + DG + BS + PL + CT
                        + 2 * F0B + 3 * F1B + FLB;
    if (ws_size < need) {
        k_sentinel<<<(out_size + 255) / 256, 256, 0, stream>>>(outp, out_size, 2000.0f);
        return;
    }
    char* p = (char*)d_ws;
    f16*   hbuf   = (f16*)p;               p += HB;
    f16*   lbuf   = (f16*)p;               p += LB;
    f16*   rbuf   = (f16*)p;               p += RB;
    float* dinv   = (float*)p;             p += DV;
    int*   rowptr = (int*)p;               p += RP;
    int*   cursor = (int*)p;               p += CU;
    int*   csr    = (int*)p;               p += CS;
    int*   deg    = (int*)p;               p += DG;
    int*   bsum   = (int*)p;               p += BS;
    float* pool   = (float*)p;             p += PL;
    float* cnt    = (float*)p;             p += CT;
    half8* F0     = (half8*)p;             p += F0B;
    half8* Fres   = (half8*)p;             p += F0B;
    half8* F1     = (half8*)p;             p += F1B;
    half8* F2     = (half8*)p;             p += F1B;
    half8* Fl0    = (half8*)p;             p += F1B;
    half8* Fl1    = (half8*)p;

    const float* x   = (const float*)d_in[0];
    const int*   ei  = (const int*)d_in[1];
    const int*   bat = (const int*)d_in[2];
    const float* W0 = (const float*)d_in[3],  *b0 = (const float*)d_in[4];
    const float* W1 = (const float*)d_in[5],  *b1 = (const float*)d_in[6];
    const float* W2 = (const float*)d_in[7],  *b2 = (const float*)d_in[8];
    const float* g0 = (const float*)d_in[9],  *be0 = (const float*)d_in[10];
    const float* g1 = (const float*)d_in[11], *be1 = (const float*)d_in[12];
    const float* g2 = (const float*)d_in[13], *be2 = (const float*)d_in[14];
    const float* Wres = (const float*)d_in[15], *bres = (const float*)d_in[16];
    const float* Wl0 = (const float*)d_in[17], *bl0 = (const float*)d_in[18];
    const float* Wl1 = (const float*)d_in[19], *bl1 = (const float*)d_in[20];

    const int* src = ei;
    const int* dst = ei + NE;

    const int gN   = NBLK;                        // 391
    const int gE   = (NE + 255) / 256;            // 6250
    const int gRow = (NN + 63) / 64;              // 1563
    const int gGat = (NN * 64) / 256;             // 25000

    // ---- degrees + CSR build + weight conversion ----
    k_init<<<gN, 256, 0, stream>>>(deg, pool, cnt);
    k_deg<<<gE, 256, 0, stream>>>(dst, deg);
    k_wconv<<<60, 256, 0, stream>>>(W0, Wres, W1, W2, Wl0, Wl1,
                                    F0, Fres, F1, F2, Fl0, Fl1);
    k_scan_blk<<<gN, 256, 0, stream>>>(deg, rowptr, bsum);
    k_scan_top<<<1, 256, 0, stream>>>(bsum);
    k_scan_add<<<gN, 256, 0, stream>>>(rowptr, bsum);
    k_dinv_cur<<<gN, 256, 0, stream>>>(deg, rowptr, dinv, cursor);
    k_fill<<<gE, 256, 0, stream>>>(src, dst, cursor, csr);

    // ---- layer 0 fused with residual: one pass over x ----
    // lbuf = f16((x@W0)*dinv), rbuf = f16(x@Wres + bres)
    k_mfma<256, 0, true><<<gRow, 256, 0, stream>>>(x, F0, Fres, bres, dinv,
                                                   lbuf, rbuf, nullptr, CIN);
    k_gather<true><<<gGat, 256, 0, stream>>>(rowptr, csr, dinv, lbuf, rbuf, hbuf, b0, g0, be0);

    // ---- layer 1 ----
    k_mfma<128, 1, false><<<gRow, 256, 0, stream>>>(hbuf, F1, nullptr, nullptr, dinv,
                                                    lbuf, nullptr, nullptr, CH);
    k_gather<false><<<gGat, 256, 0, stream>>>(rowptr, csr, dinv, lbuf, nullptr, hbuf, b1, g1, be1);

    // ---- layer 2 ----
    k_mfma<128, 1, false><<<gRow, 256, 0, stream>>>(hbuf, F2, nullptr, nullptr, dinv,
                                                    lbuf, nullptr, nullptr, CH);
    k_gather<false><<<gGat, 256, 0, stream>>>(rowptr, csr, dinv, lbuf, nullptr, hbuf, b2, g2, be2);

    // ---- mean pool over graphs (final h) ----
    k_count<<<gN, 256, 0, stream>>>(bat, cnt);
    k_pool<<<gRow, 128, 0, stream>>>(hbuf, bat, pool);
    k_pool_fin<<<(NB * CH + 255) / 256, 256, 0, stream>>>(pool, cnt, poolp);

    // ---- head MLP ----
    k_mfma<128, 2, false><<<gRow, 256, 0, stream>>>(hbuf, Fl0, nullptr, bl0, nullptr,
                                                    lbuf, nullptr, nullptr, CH);
    k_mfma<64, 3, false><<<gRow, 256, 0, stream>>>(lbuf, Fl1, nullptr, bl1, nullptr,
                                                   nullptr, nullptr, outp, CH);
}

// Round 9
// 702.899 us; speedup vs baseline: 12.6684x; 1.1333x over previous
//
#include <hip/hip_runtime.h>
#include <hip/hip_fp16.h>

typedef __half f16;
typedef _Float16 half8 __attribute__((ext_vector_type(8)));
typedef float floatx4 __attribute__((ext_vector_type(4)));

#define NN   100000   // nodes
#define NE   1600000  // edges
#define CIN  256
#define CH   128
#define COUT 64
#define NB   64

#define NBUK 128      // CSR buckets
#define NPB  782      // nodes per bucket (128*782 = 100096 >= NN)
#define BCAP 32       // LDS bin slots per bucket (k_bin)
#define CAPB 20480    // staging capacity per bucket (mean 12500, +72 sigma)
#define G1   512      // k_bin blocks
#define EPB  3125     // edges per k_bin block
#define CSZ  15104    // k_csr LDS csr entries (60.4KB; mean 12500, +23 sigma)

// ---------------- diagnostics ----------------
__global__ void k_sentinel(float* __restrict__ out, int n, float val) {
    int i = blockIdx.x * 256 + threadIdx.x;
    if (i < n) out[i] = val;
}

// ---------------- init: pool/cnt zero, bucket cursors ----------------
__global__ void k_init(float* __restrict__ pool, float* __restrict__ cnt,
                       int* __restrict__ gcur) {
    int i = blockIdx.x * 256 + threadIdx.x;
    if (i < NB * CH) pool[i] = 0.0f;
    if (i < NB) cnt[i] = 0.0f;
    if (i < NBUK) gcur[i] = i * CAPB;
}

// ---------------- phase 1: bin edges by dst bucket ----------------
// stage[gcur[b]++] = (dst%NPB)<<17 | src, flushed in 16-entry (64B) chunks.
__global__ __launch_bounds__(256) void k_bin(const int* __restrict__ src,
                                             const int* __restrict__ dst,
                                             int* __restrict__ gcur,
                                             int* __restrict__ stage) {
    __shared__ int bins[NBUK][BCAP];
    __shared__ int bcnt[NBUK];
    __shared__ int fcnt[NBUK];
    __shared__ int fbase[NBUK];
    const int tid = threadIdx.x;
    if (tid < NBUK) bcnt[tid] = 0;
    __syncthreads();
    const int e0 = blockIdx.x * EPB;
    const int e1 = (e0 + EPB < NE) ? e0 + EPB : NE;
    for (int base = e0; base < e1; base += 256) {
        int e = base + tid;
        if (e < e1) {
            int s = src[e], d = dst[e];
            int bk = d / NPB;                       // magic-mul (const)
            int pk = ((d - bk * NPB) << 17) | s;
            int pos = atomicAdd(&bcnt[bk], 1);
            if (pos < BCAP) {
                bins[bk][pos] = pk;
            } else {                                 // rare in-round overflow
                int gp = atomicAdd(&gcur[bk], 1);
                if (gp < (bk + 1) * CAPB) stage[gp] = pk;
            }
        }
        __syncthreads();
        if (tid < NBUK) {                            // plan flush
            int stored = bcnt[tid]; if (stored > BCAP) stored = BCAP;
            int nf = stored & ~15;                   // 0,16,32
            fcnt[tid] = nf;
            if (nf) fbase[tid] = atomicAdd(&gcur[tid], nf);
        }
        __syncthreads();
#pragma unroll
        for (int pass = 0; pass < NBUK / 16; ++pass) {   // coalesced flush
            int b = pass * 16 + (tid >> 4);
            int sl = tid & 15;
            int nf = fcnt[b];
            int fb = fbase[b];
            for (int k = sl; k < nf; k += 16)
                if (fb + k < (b + 1) * CAPB) stage[fb + k] = bins[b][k];
        }
        __syncthreads();
        if (tid < NBUK) {                            // compact remainder
            int stored = bcnt[tid]; if (stored > BCAP) stored = BCAP;
            int nf = fcnt[tid];
            for (int k = nf; k < stored; ++k) bins[tid][k - nf] = bins[tid][k];
            bcnt[tid] = stored - nf;
        }
        __syncthreads();
    }
    // final partial flush
    if (tid < NBUK) {
        int stored = bcnt[tid];
        fcnt[tid] = stored;
        if (stored) fbase[tid] = atomicAdd(&gcur[tid], stored);
    }
    __syncthreads();
#pragma unroll
    for (int pass = 0; pass < NBUK / 16; ++pass) {
        int b = pass * 16 + (tid >> 4);
        int sl = tid & 15;
        int nf = fcnt[b];
        int fb = fbase[b];
        for (int k = sl; k < nf; k += 16)
            if (fb + k < (b + 1) * CAPB) stage[fb + k] = bins[b][k];
    }
}

// ---------------- phase 1b: scan bucket totals -> csr bases ----------------
__global__ void k_gtot(const int* __restrict__ gcur, int* __restrict__ barr,
                       int* __restrict__ rowptr) {
    int lane = threadIdx.x;   // 64 threads
    int carry = 0;
    for (int c0 = 0; c0 < NBUK; c0 += 64) {
        int idx = c0 + lane;
        int orig = gcur[idx] - idx * CAPB;
        int v = orig;
#pragma unroll
        for (int off = 1; off < 64; off <<= 1) {
            int t = __shfl_up(v, off);
            if (lane >= off) v += t;
        }
        barr[idx] = v - orig + carry;
        carry += __shfl(v, 63);
    }
    if (lane == 0) rowptr[NN] = NE;
}

// ---------------- phase 2: per-bucket CSR + rowptr + dinv ----------------
__global__ __launch_bounds__(256) void k_csr(const int* __restrict__ gcur,
                                             const int* __restrict__ barr,
                                             const int* __restrict__ stage,
                                             int* __restrict__ rowptr,
                                             int* __restrict__ csr,
                                             float* __restrict__ dinv) {
    __shared__ int hist[NPB];
    __shared__ int lcsr[CSZ];
    const int b = blockIdx.x, tid = threadIdx.x;
    const int nbase = b * NPB;
    const int nloc = (NPB < NN - nbase) ? NPB : NN - nbase;
    const int count = gcur[b] - b * CAPB;
    const int gbase = barr[b];
    const int sb = b * CAPB;
    for (int i = tid; i < NPB; i += 256) hist[i] = 0;
    __syncthreads();
    for (int i = tid; i < count; i += 256)
        atomicAdd(&hist[stage[sb + i] >> 17], 1);
    __syncthreads();
    for (int dl = tid; dl < nloc; dl += 256)
        dinv[nbase + dl] = rsqrtf((float)hist[dl] + 1.0f);
    __syncthreads();
    if (tid < 64) {                       // wave-0 exclusive scan of hist
        int carry = 0;
        for (int c0 = 0; c0 < NPB; c0 += 64) {
            int idx = c0 + tid;
            int orig = (idx < NPB) ? hist[idx] : 0;
            int v = orig;
#pragma unroll
            for (int off = 1; off < 64; off <<= 1) {
                int t = __shfl_up(v, off);
                if (tid >= off) v += t;
            }
            if (idx < NPB) hist[idx] = v - orig + carry;
            carry += __shfl(v, 63);
        }
    }
    __syncthreads();
    for (int dl = tid; dl < nloc; dl += 256)
        rowptr[nbase + dl] = gbase + hist[dl];
    __syncthreads();
    const bool fits = (count <= CSZ);
    for (int i = tid; i < count; i += 256) {
        int pk = stage[sb + i];
        int dl = pk >> 17, s = pk & 0x1FFFF;
        int pos = atomicAdd(&hist[dl], 1);
        if (fits) lcsr[pos] = s;
        else csr[gbase + pos] = s;        // fallback (pathological skew only)
    }
    __syncthreads();
    if (fits)
        for (int i = tid; i < count; i += 256) csr[gbase + i] = lcsr[i];
}

// ---------------- weight -> f16 fragment-major conversion ----------------
__global__ __launch_bounds__(256) void k_wconv(
        const float* __restrict__ W0, const float* __restrict__ Wres,
        const float* __restrict__ W1, const float* __restrict__ W2,
        const float* __restrict__ Wl0, const float* __restrict__ Wl1,
        half8* __restrict__ F0, half8* __restrict__ Fres,
        half8* __restrict__ F1, half8* __restrict__ F2,
        half8* __restrict__ Fl0, half8* __restrict__ Fl1) {
    int f = blockIdx.x * 256 + threadIdx.x;
    const float* W; half8* F; int M, base;
    if      (f <  4096) { W = W0;   F = F0;   M = 128; base = 0; }
    else if (f <  8192) { W = Wres; F = Fres; M = 128; base = 4096; }
    else if (f < 10240) { W = W1;   F = F1;   M = 128; base = 8192; }
    else if (f < 12288) { W = W2;   F = F2;   M = 128; base = 10240; }
    else if (f < 14336) { W = Wl0;  F = Fl0;  M = 128; base = 12288; }
    else if (f < 15360) { W = Wl1;  F = Fl1;  M = 64;  base = 14336; }
    else return;
    int fl = f - base;
    int lane = fl & 63, fm = lane & 15, g = lane >> 4;
    int rest = fl >> 6;
    int nt = M / 16;
    int t = rest % nt, kt = rest / nt;
    half8 v;
#pragma unroll
    for (int j = 0; j < 8; ++j)
        v[j] = (_Float16)W[(size_t)(kt * 32 + g * 8 + j) * M + t * 16 + fm];
    F[fl] = v;
}

// ---------------- MFMA GEMM ----------------
// C[N,M] = A[N,K] @ W[K,M]; 256 thr, 64 rows x M cols; B-frags from global.
template <int M, int EPI, bool AF32>
__global__ __launch_bounds__(256) void k_mfma(const void* __restrict__ Av,
                                              const half8* __restrict__ WF,
                                              const half8* __restrict__ WFb,
                                              const float* __restrict__ bias,
                                              const float* __restrict__ dinv,
                                              f16* __restrict__ lout,
                                              f16* __restrict__ rout,
                                              float* __restrict__ fout,
                                              int K) {
    constexpr int KC = 32, APAD = 40;
    constexpr int NT = M / 16;
    __shared__ _Float16 Al[64 * APAD];
    const int tid = threadIdx.x;
    const int wave = tid >> 6, lane = tid & 63;
    const int fm = lane & 15, g = lane >> 4;
    const int rb = blockIdx.x * 64;

    floatx4 acc[NT];
#pragma unroll
    for (int t = 0; t < NT; ++t)
#pragma unroll
        for (int r = 0; r < 4; ++r) acc[t][r] = 0.0f;

    const int arow = tid >> 2;
    const int koff = (tid & 3) * 8;

    for (int k0 = 0, kt = 0; k0 < K; k0 += KC, ++kt) {
        __syncthreads();
        {
            int grow = rb + arow;
            half8 av;
            if (grow < NN) {
                if (AF32) {
                    const float* ap = (const float*)Av + (size_t)grow * K + k0 + koff;
                    float4 v0 = *(const float4*)ap;
                    float4 v1 = *(const float4*)(ap + 4);
                    av[0] = (_Float16)v0.x; av[1] = (_Float16)v0.y;
                    av[2] = (_Float16)v0.z; av[3] = (_Float16)v0.w;
                    av[4] = (_Float16)v1.x; av[5] = (_Float16)v1.y;
                    av[6] = (_Float16)v1.z; av[7] = (_Float16)v1.w;
                } else {
                    av = *(const half8*)((const _Float16*)Av + (size_t)grow * K + k0 + koff);
                }
            } else {
#pragma unroll
                for (int i = 0; i < 8; ++i) av[i] = (_Float16)0.0f;
            }
            *(half8*)&Al[arow * APAD + koff] = av;
        }
        __syncthreads();
        half8 afrag = *(const half8*)&Al[(wave * 16 + fm) * APAD + g * 8];
#pragma unroll
        for (int t = 0; t < NT; ++t) {
            half8 bfrag;
            if (EPI == 0) {
                bfrag = (t < 8) ? WF[((size_t)kt * 8 + t) * 64 + lane]
                                : WFb[((size_t)kt * 8 + (t - 8)) * 64 + lane];
            } else {
                bfrag = WF[((size_t)kt * NT + t) * 64 + lane];
            }
            acc[t] = __builtin_amdgcn_mfma_f32_16x16x32_f16(afrag, bfrag, acc[t], 0, 0, 0);
        }
    }
    const int rloc = wave * 16 + g * 4;
#pragma unroll
    for (int t = 0; t < NT; ++t) {
        int col = t * 16 + fm;
#pragma unroll
        for (int r = 0; r < 4; ++r) {
            int row = rb + rloc + r;
            if (row >= NN) continue;
            float v = acc[t][r];
            if (EPI == 0) {
                if (col < 128) lout[(size_t)row * 128 + col] = (f16)(v * dinv[row]);
                else           rout[(size_t)row * 128 + (col - 128)] = (f16)(v + bias[col - 128]);
            } else if (EPI == 1) {
                lout[(size_t)row * M + col] = (f16)(v * dinv[row]);
            } else if (EPI == 2) {
                lout[(size_t)row * M + col] = (f16)fmaxf(v + bias[col], 0.0f);
            } else {
                fout[(size_t)row * M + col] = v + bias[col];
            }
        }
    }
}

// ---------------- CSR gather + BN + ReLU (+residual) ----------------
template <bool RES>
__global__ __launch_bounds__(256) void k_gather(const int* __restrict__ rowptr,
                                                const int* __restrict__ csr,
                                                const float* __restrict__ dinv,
                                                const f16* __restrict__ lin,
                                                const f16* __restrict__ res,
                                                f16* __restrict__ h,
                                                const float* __restrict__ b,
                                                const float* __restrict__ g,
                                                const float* __restrict__ be) {
    const int gw = (blockIdx.x * 256 + threadIdx.x) >> 6;
    const int lane = threadIdx.x & 63;
    if (gw >= NN) return;
    const __half2* lp = (const __half2*)lin;
    const int start = rowptr[gw], end = rowptr[gw + 1];

    float2 acc = __half22float2(lp[(size_t)gw * 64 + lane]);  // self term
    int j = start;
    for (; j + 7 < end; j += 8) {
        int s0 = csr[j],     s1 = csr[j + 1], s2 = csr[j + 2], s3 = csr[j + 3];
        int s4 = csr[j + 4], s5 = csr[j + 5], s6 = csr[j + 6], s7 = csr[j + 7];
        float2 v0 = __half22float2(lp[(size_t)s0 * 64 + lane]);
        float2 v1 = __half22float2(lp[(size_t)s1 * 64 + lane]);
        float2 v2 = __half22float2(lp[(size_t)s2 * 64 + lane]);
        float2 v3 = __half22float2(lp[(size_t)s3 * 64 + lane]);
        float2 v4 = __half22float2(lp[(size_t)s4 * 64 + lane]);
        float2 v5 = __half22float2(lp[(size_t)s5 * 64 + lane]);
        float2 v6 = __half22float2(lp[(size_t)s6 * 64 + lane]);
        float2 v7 = __half22float2(lp[(size_t)s7 * 64 + lane]);
        acc.x += ((v0.x + v1.x) + (v2.x + v3.x)) + ((v4.x + v5.x) + (v6.x + v7.x));
        acc.y += ((v0.y + v1.y) + (v2.y + v3.y)) + ((v4.y + v5.y) + (v6.y + v7.y));
    }
    for (; j + 3 < end; j += 4) {
        int s0 = csr[j], s1 = csr[j + 1], s2 = csr[j + 2], s3 = csr[j + 3];
        float2 v0 = __half22float2(lp[(size_t)s0 * 64 + lane]);
        float2 v1 = __half22float2(lp[(size_t)s1 * 64 + lane]);
        float2 v2 = __half22float2(lp[(size_t)s2 * 64 + lane]);
        float2 v3 = __half22float2(lp[(size_t)s3 * 64 + lane]);
        acc.x += (v0.x + v1.x) + (v2.x + v3.x);
        acc.y += (v0.y + v1.y) + (v2.y + v3.y);
    }
    for (; j < end; ++j) {
        int s = csr[j];
        float2 v = __half22float2(lp[(size_t)s * 64 + lane]);
        acc.x += v.x;
        acc.y += v.y;
    }
    const float inv_sqrt = 0.99999500003749968f;  // 1/sqrt(1+1e-5)
    float dv = dinv[gw];
    int f = lane * 2;
    float2 bb = *(const float2*)&b[f];
    float2 gg = *(const float2*)&g[f];
    float2 ee = *(const float2*)&be[f];
    float t0 = fmaxf((acc.x * dv + bb.x) * (gg.x * inv_sqrt) + ee.x, 0.0f);
    float t1 = fmaxf((acc.y * dv + bb.y) * (gg.y * inv_sqrt) + ee.y, 0.0f);
    if (RES) {
        float2 rv = __half22float2(((const __half2*)res)[(size_t)gw * 64 + lane]);
        t0 += rv.x;
        t1 += rv.y;
    }
    ((__half2*)h)[(size_t)gw * 64 + lane] = __floats2half2_rn(t0, t1);
}

// ---------------- pooling ----------------
__global__ void k_count(const int* __restrict__ batch, float* __restrict__ cnt) {
    __shared__ float hist[NB];
    int tid = threadIdx.x;
    if (tid < NB) hist[tid] = 0.0f;
    __syncthreads();
    int n = blockIdx.x * 256 + tid;
    if (n < NN) atomicAdd(&hist[batch[n]], 1.0f);
    __syncthreads();
    if (tid < NB && hist[tid] != 0.0f) atomicAdd(&cnt[tid], hist[tid]);
}

__global__ void k_pool(const f16* __restrict__ h, const int* __restrict__ batch,
                       float* __restrict__ pool) {
    int n0 = blockIdx.x * 64;
    int j = threadIdx.x;
    int cur = batch[n0];
    float acc = 0.0f;
    int nend = (n0 + 64 < NN) ? n0 + 64 : NN;
    for (int n = n0; n < nend; ++n) {
        int b = batch[n];
        if (b != cur) {
            atomicAdd(&pool[cur * CH + j], acc);
            acc = 0.0f;
            cur = b;
        }
        acc += (float)h[(size_t)n * CH + j];
    }
    atomicAdd(&pool[cur * CH + j], acc);
}

__global__ void k_pool_fin(const float* __restrict__ pool,
                           const float* __restrict__ cnt,
                           float* __restrict__ out) {
    int i = blockIdx.x * 256 + threadIdx.x;
    if (i < NB * CH) {
        float c = fmaxf(cnt[i / CH], 1.0f);
        out[i] = pool[i] / c;
    }
}

// ---------------- launch ----------------
extern "C" void kernel_launch(void* const* d_in, const int* in_sizes, int n_in,
                              void* d_out, int out_size, void* d_ws, size_t ws_size,
                              hipStream_t stream) {
    float* outp  = (float*)d_out;                  // [NN, COUT] f32
    float* poolp = outp + (size_t)NN * COUT;       // [NB, CH] f32

    // ---- workspace layout (~84.2 MB; stage aliases rbuf) ----
    const size_t HB = (size_t)NN * CH * 2;         // f16 h          25.6 MB
    const size_t LB = (size_t)NN * CH * 2;         // f16 linscaled  25.6 MB
    const size_t RB = (size_t)NN * CH * 2;         // f16 residual / stage alias
    const size_t DV = (size_t)NN * 4;
    const size_t RP = 400016;                      // (NN+1)*4 padded to 16
    const size_t CS = (size_t)NE * 4;
    const size_t GC = 512;                         // gcur 128 ints
    const size_t BA = 528;                         // barr 128+pad
    const size_t PL = (size_t)NB * CH * 4;
    const size_t CT = 256;
    const size_t F0B = 4096 * 16, F1B = 2048 * 16, FLB = 1024 * 16;
    const size_t need = HB + LB + RB + DV + RP + CS + GC + BA + PL + CT
                        + 2 * F0B + 3 * F1B + FLB;
    if (ws_size < need) {
        k_sentinel<<<(out_size + 255) / 256, 256, 0, stream>>>(outp, out_size, 2000.0f);
        return;
    }
    char* p = (char*)d_ws;
    f16*   hbuf   = (f16*)p;               p += HB;
    f16*   lbuf   = (f16*)p;               p += LB;
    f16*   rbuf   = (f16*)p;
    int*   stage  = (int*)p;               p += RB;   // alias: stage used before rbuf
    float* dinv   = (float*)p;             p += DV;
    int*   rowptr = (int*)p;               p += RP;
    int*   csr    = (int*)p;               p += CS;
    int*   gcur   = (int*)p;               p += GC;
    int*   barr   = (int*)p;               p += BA;
    float* pool   = (float*)p;             p += PL;
    float* cnt    = (float*)p;             p += CT;
    half8* F0     = (half8*)p;             p += F0B;
    half8* Fres   = (half8*)p;             p += F0B;
    half8* F1     = (half8*)p;             p += F1B;
    half8* F2     = (half8*)p;             p += F1B;
    half8* Fl0    = (half8*)p;             p += F1B;
    half8* Fl1    = (half8*)p;

    const float* x   = (const float*)d_in[0];
    const int*   ei  = (const int*)d_in[1];
    const int*   bat = (const int*)d_in[2];
    const float* W0 = (const float*)d_in[3],  *b0 = (const float*)d_in[4];
    const float* W1 = (const float*)d_in[5],  *b1 = (const float*)d_in[6];
    const float* W2 = (const float*)d_in[7],  *b2 = (const float*)d_in[8];
    const float* g0 = (const float*)d_in[9],  *be0 = (const float*)d_in[10];
    const float* g1 = (const float*)d_in[11], *be1 = (const float*)d_in[12];
    const float* g2 = (const float*)d_in[13], *be2 = (const float*)d_in[14];
    const float* Wres = (const float*)d_in[15], *bres = (const float*)d_in[16];
    const float* Wl0 = (const float*)d_in[17], *bl0 = (const float*)d_in[18];
    const float* Wl1 = (const float*)d_in[19], *bl1 = (const float*)d_in[20];

    const int* src = ei;
    const int* dst = ei + NE;

    const int gRow = (NN + 63) / 64;              // 1563
    const int gGat = (NN * 64) / 256;             // 25000

    // ---- CSR build: bin -> bucket scan -> per-bucket CSR/rowptr/dinv ----
    k_init<<<33, 256, 0, stream>>>(pool, cnt, gcur);
    k_wconv<<<60, 256, 0, stream>>>(W0, Wres, W1, W2, Wl0, Wl1,
                                    F0, Fres, F1, F2, Fl0, Fl1);
    k_bin<<<G1, 256, 0, stream>>>(src, dst, gcur, stage);
    k_gtot<<<1, 64, 0, stream>>>(gcur, barr, rowptr);
    k_csr<<<NBUK, 256, 0, stream>>>(gcur, barr, stage, rowptr, csr, dinv);

    // ---- layer 0 fused with residual: one pass over x ----
    k_mfma<256, 0, true><<<gRow, 256, 0, stream>>>(x, F0, Fres, bres, dinv,
                                                   lbuf, rbuf, nullptr, CIN);
    k_gather<true><<<gGat, 256, 0, stream>>>(rowptr, csr, dinv, lbuf, rbuf, hbuf, b0, g0, be0);

    // ---- layer 1 ----
    k_mfma<128, 1, false><<<gRow, 256, 0, stream>>>(hbuf, F1, nullptr, nullptr, dinv,
                                                    lbuf, nullptr, nullptr, CH);
    k_gather<false><<<gGat, 256, 0, stream>>>(rowptr, csr, dinv, lbuf, nullptr, hbuf, b1, g1, be1);

    // ---- layer 2 ----
    k_mfma<128, 1, false><<<gRow, 256, 0, stream>>>(hbuf, F2, nullptr, nullptr, dinv,
                                                    lbuf, nullptr, nullptr, CH);
    k_gather<false><<<gGat, 256, 0, stream>>>(rowptr, csr, dinv, lbuf, nullptr, hbuf, b2, g2, be2);

    // ---- mean pool over graphs (final h) ----
    k_count<<<(NN + 255) / 256, 256, 0, stream>>>(bat, cnt);
    k_pool<<<gRow, 128, 0, stream>>>(hbuf, bat, pool);
    k_pool_fin<<<(NB * CH + 255) / 256, 256, 0, stream>>>(pool, cnt, poolp);

    // ---- head MLP ----
    k_mfma<128, 2, false><<<gRow, 256, 0, stream>>>(hbuf, Fl0, nullptr, bl0, nullptr,
                                                    lbuf, nullptr, nullptr, CH);
    k_mfma<64, 3, false><<<gRow, 256, 0, stream>>>(lbuf, Fl1, nullptr, bl1, nullptr,
                                                   nullptr, nullptr, outp, CH);
}